// Round 10
// baseline (142.072 us; speedup 1.0000x reference)
//
#include <hip/hip_runtime.h>
#include <hip/hip_bf16.h>
#include <cstdint>

#define EL 1048576ull   // 1Mi elements

typedef __bf16 bf16_t;
typedef bf16_t bf16x8 __attribute__((ext_vector_type(8)));
typedef float  f32x4  __attribute__((ext_vector_type(4)));
typedef unsigned int u32x2 __attribute__((ext_vector_type(2)));
typedef unsigned int u32x4 __attribute__((ext_vector_type(4)));

__device__ __forceinline__ unsigned short f2bf(float f) {
  unsigned int u = __builtin_bit_cast(unsigned int, f);
  u += 0x7FFFu + ((u >> 16) & 1u);   // RNE
  return (unsigned short)(u >> 16);
}

// pack 2 f32 -> 2 bf16 in one u32 (lo -> low half), RNE; proven round 5
__device__ __forceinline__ unsigned int cvtpk(float lo, float hi2) {
  unsigned int r;
  asm("v_cvt_pk_bf16_f32 %0, %1, %2" : "=v"(r) : "v"(lo), "v"(hi2));
  return r;
}

__device__ __forceinline__ float fexp2(float x) {
#if __has_builtin(__builtin_amdgcn_exp2f)
  return __builtin_amdgcn_exp2f(x);
#else
  return exp2f(x);
#endif
}

typedef __attribute__((address_space(1))) void as1_void;
typedef __attribute__((address_space(3))) void as3_void;
__device__ __forceinline__ void load_lds16(const void* g, void* l) {
  __builtin_amdgcn_global_load_lds((as1_void*)g, (as3_void*)l, 16, 0, 0);
}

// P repack via permlane swaps (VALU, no LDS pipe); proven round 6
__device__ __forceinline__ bf16x8 repack_af(const f32x4 s0v, const f32x4 s1v) {
  unsigned int c00 = cvtpk(s0v[0], s0v[1]);
  unsigned int c01 = cvtpk(s0v[2], s0v[3]);
  unsigned int c10 = cvtpk(s1v[0], s1v[1]);
  unsigned int c11 = cvtpk(s1v[2], s1v[3]);
  asm("v_permlane32_swap_b32 %0, %1" : "+v"(c00), "+v"(c10));
  asm("v_permlane16_swap_b32 %0, %1" : "+v"(c00), "+v"(c10));
  asm("v_permlane32_swap_b32 %0, %1" : "+v"(c01), "+v"(c11));
  asm("v_permlane16_swap_b32 %0, %1" : "+v"(c01), "+v"(c11));
  u32x4 wd; wd[0] = c00; wd[1] = c01; wd[2] = c10; wd[3] = c11;
  return __builtin_bit_cast(bf16x8, wd);
}

// ---------------------------------------------------------------- convert weights only
// wq/wk/wv/wo (f32, 1M elems each) -> ws[0..4EL) bf16. A-matrices are converted
// in-flight inside qkv_gemm staging (read-once data; avoids 48MB of round-trip).
__global__ __launch_bounds__(256) void convert_w(
    const float* __restrict__ wq, const float* __restrict__ wk,
    const float* __restrict__ wv, const float* __restrict__ wo,
    unsigned short* __restrict__ ws)
{
  for (size_t v4 = (size_t)blockIdx.x * blockDim.x + threadIdx.x; v4 < EL;
       v4 += (size_t)gridDim.x * blockDim.x) {
    size_t e = v4 * 4;
    unsigned seg = (unsigned)(e >> 20);
    const float* s = (seg == 0) ? wq : (seg == 1) ? wk : (seg == 2) ? wv : wo;
    const float4 f = *(const float4*)(s + (e & (EL - 1)));
    ushort4 o;
    o.x = f2bf(f.x); o.y = f2bf(f.y); o.z = f2bf(f.z); o.w = f2bf(f.w);
    *(ushort4*)(ws + e) = o;
  }
}

// ---------------------------------------------------------------- GEMM main loop (acc += A * B^T)
// B: [1024][1024] bf16 (row n holds B[n][k]). A: bf16 [M][1024], or f32 [M][1024]
// with in-flight bf16 conversion (AF32). XOR-swizzled LDS, identical layout both paths.
template <int BM, int BN, int WM, int WN, bool AF32>
__device__ __forceinline__ void gemm_bt_main(
    const void* __restrict__ A,
    const unsigned short* __restrict__ B,
    f32x4 (&acc)[BM / WM / 16][BN / WN / 16])
{
  constexpr int K = 1024, BK = 64;
  constexpr int AM = BM / WM / 16, AN = BN / WN / 16;
  __shared__ __align__(16) unsigned short sA[BM * BK];
  __shared__ __align__(16) unsigned short sB[BN * BK];
  const int tid  = threadIdx.x;
  const int wave = tid >> 6, lane = tid & 63;
  const int wm = wave / WN, wn = wave % WN;
  const int tm = blockIdx.y * BM, tn = blockIdx.x * BN;
  const int l16 = lane & 15, hi = lane >> 4, swz = l16 & 7;

  for (int k0 = 0; k0 < K; k0 += BK) {
    __syncthreads();
    if constexpr (AF32) {
      const float* Af = (const float*)A;
#pragma unroll
      for (int i = 0; i < BM * 8 / 256; i++) {
        int p = i * 256 + tid;
        int row = p >> 3, c = p & 7;
        const float* src = Af + (size_t)(tm + row) * K + k0 + ((c ^ (row & 7)) * 8);
        float4 f0 = *(const float4*)src;
        float4 f1 = *(const float4*)(src + 4);
        u32x4 w;
        w[0] = cvtpk(f0.x, f0.y); w[1] = cvtpk(f0.z, f0.w);
        w[2] = cvtpk(f1.x, f1.y); w[3] = cvtpk(f1.z, f1.w);
        *(u32x4*)&sA[(size_t)p * 8] = w;
      }
    } else {
      const unsigned short* Ab = (const unsigned short*)A;
#pragma unroll
      for (int i = 0; i < BM * 8 / 256; i++) {
        int p = i * 256 + tid;
        int row = p >> 3, c = p & 7;
        load_lds16(Ab + (size_t)(tm + row) * K + k0 + ((c ^ (row & 7)) * 8),
                   &sA[(i * 256 + wave * 64) * 8]);
      }
    }
#pragma unroll
    for (int i = 0; i < BN * 8 / 256; i++) {
      int p = i * 256 + tid;
      int row = p >> 3, c = p & 7;
      load_lds16(B + (size_t)(tn + row) * K + k0 + ((c ^ (row & 7)) * 8),
                 &sB[(i * 256 + wave * 64) * 8]);
    }
    __syncthreads();

#pragma unroll
    for (int kk = 0; kk < 2; kk++) {
      bf16x8 af[AM], bfr[AN];
#pragma unroll
      for (int i = 0; i < AM; i++) {
        int row = wm * (BM / WM) + i * 16 + l16;
        af[i] = *(const bf16x8*)&sA[row * BK + (((kk * 4 + hi) ^ swz) * 8)];
      }
#pragma unroll
      for (int j = 0; j < AN; j++) {
        int row = wn * (BN / WN) + j * 16 + l16;
        bfr[j] = *(const bf16x8*)&sB[row * BK + (((kk * 4 + hi) ^ swz) * 8)];
      }
#pragma unroll
      for (int i = 0; i < AM; i++)
#pragma unroll
        for (int j = 0; j < AN; j++)
          acc[i][j] = __builtin_amdgcn_mfma_f32_16x16x32_bf16(af[i], bfr[j], acc[i][j], 0, 0, 0);
    }
  }
}

// ---------------------------------------------------------------- QKV projections (A = f32 inputs)
__global__ __launch_bounds__(256, 3) void qkv_gemm(
    const float* q, const float* k, const float* v,
    const unsigned short* wqb, const unsigned short* wkb, const unsigned short* wvb,
    const float* bq, const float* bk, const float* bv,
    unsigned short* Qp, unsigned short* Kp, unsigned short* Vt)
{
  const float* A; const unsigned short* B; const float* bias;
  if (blockIdx.z == 0)      { A = q; B = wqb; bias = bq; }
  else if (blockIdx.z == 1) { A = k; B = wkb; bias = bk; }
  else                      { A = v; B = wvb; bias = bv; }

  f32x4 acc[4][4] = {};
  gemm_bt_main<128, 128, 2, 2, true>(A, B, acc);

  const int tid = threadIdx.x, wave = tid >> 6, lane = tid & 63;
  const int wm = wave >> 1, wn = wave & 1;
  const int tm = blockIdx.y * 128, tn = blockIdx.x * 128;
  const int l16 = lane & 15, hi = lane >> 4;

  if (blockIdx.z < 2) {
    unsigned short* C = (blockIdx.z == 0) ? Qp : Kp;
    const float scale = (blockIdx.z == 0) ? 0.18033688011112042f : 1.0f; // 0.125*log2(e)
#pragma unroll
    for (int i = 0; i < 4; i++) {
      int row0 = tm + wm * 64 + i * 16 + hi * 4;
#pragma unroll
      for (int j = 0; j < 4; j++) {
        int col = tn + wn * 64 + j * 16 + l16;
        float bv2 = bias[col];
#pragma unroll
        for (int r = 0; r < 4; r++)
          C[(size_t)(row0 + r) * 1024 + col] = f2bf((acc[i][j][r] + bv2) * scale);
      }
    }
  } else {
    // transposed V write: lane's 4 rows are 4 consecutive s -> one 8B store
#pragma unroll
    for (int i = 0; i < 4; i++) {
      int row0 = tm + wm * 64 + i * 16 + hi * 4;
      int bb = row0 >> 11, s = row0 & 2047;
#pragma unroll
      for (int j = 0; j < 4; j++) {
        int col = tn + wn * 64 + j * 16 + l16;
        int hh = col >> 6, d = col & 63;
        float bv2 = bias[col];
        u32x2 w;
        w[0] = cvtpk(acc[i][j][0] + bv2, acc[i][j][1] + bv2);
        w[1] = cvtpk(acc[i][j][2] + bv2, acc[i][j][3] + bv2);
        *(u32x2*)&Vt[((size_t)(bb * 16 + hh) * 64 + d) * 2048 + s] = w;
      }
    }
  }
}

__global__ __launch_bounds__(256, 2) void out_gemm(
    const unsigned short* Yb, const unsigned short* wob, const float* bo, float* out)
{
  f32x4 acc[2][4] = {};
  gemm_bt_main<128, 64, 4, 1, false>(Yb, wob, acc);

  const int tid = threadIdx.x, wave = tid >> 6, lane = tid & 63;
  const int tm = blockIdx.y * 128, tn = blockIdx.x * 64;
  const int l16 = lane & 15, hi = lane >> 4;
#pragma unroll
  for (int i = 0; i < 2; i++) {
    int row0 = tm + wave * 32 + i * 16 + hi * 4;
#pragma unroll
    for (int j = 0; j < 4; j++) {
      int col = tn + j * 16 + l16;
      float bv2 = bo[col];
#pragma unroll
      for (int r = 0; r < 4; r++)
        out[(size_t)(row0 + r) * 1024 + col] = acc[i][j][r] + bv2;
    }
  }
}

// ---------------------------------------------------------------- flash attention
// 8 waves x 32 q-rows = 256 q per block, full kv sweep (16 tiles of 128).
// Swapped QK^T (log2 domain, scale folded into Q projection), constant-max softmax
// (P = exp2(s-16), shift-invariant), permlane P repack, double-buffered K/V staging
// with counted vmcnt + pointer-marched sources, setprio on MFMA clusters.
__global__ __launch_bounds__(512, 4) void attn_kernel(
    const unsigned short* __restrict__ Qp, const unsigned short* __restrict__ Kp,
    const unsigned short* __restrict__ Vt, const int* __restrict__ mask,
    unsigned short* __restrict__ Yb)
{
  constexpr int S = 2048, H = 1024;
  __shared__ __align__(16) unsigned short sK[2][128 * 64];  // K tiles (also Q staging)
  __shared__ __align__(16) unsigned short sV[2][64 * 128];  // V^T tiles [d][kv]

  const int tid = threadIdx.x, wave = tid >> 6, lane = tid & 63;
  const int l16 = lane & 15, hi = lane >> 4, swz = l16 & 7;
  const int qt = blockIdx.x * 256;
  const int h = blockIdx.y, b = blockIdx.z, bh = b * 16 + h;
  const unsigned short* Qb = Qp + (size_t)b * S * H + (size_t)h * 64;
  const unsigned short* Kb = Kp + (size_t)b * S * H + (size_t)h * 64;
  const unsigned short* Vb = Vt + (size_t)bh * 64 * 2048;

  // loop-invariant LDS read offsets (shorts)
  const int kinv0 = l16 * 64 + ((hi ^ swz) * 8);
  const int kinv1 = l16 * 64 + (((4 + hi) ^ swz) * 8);
  const int vinv0 = l16 * 128 + ((hi ^ swz) * 8);
  const int vinv1 = l16 * 128 + (((4 + hi) ^ swz) * 8);

  // ---- stage Q tile (256x64, 32KB) into sK[0..1], read frags, then release
  unsigned short* sQ = &sK[0][0];
#pragma unroll
  for (int i = 0; i < 4; i++) {
    int p = i * 512 + tid, row = p >> 3, c = p & 7;
    load_lds16(Qb + (size_t)(qt + row) * H + ((c ^ (row & 7)) * 8),
               &sQ[(i * 512 + wave * 64) * 8]);
  }
  asm volatile("s_waitcnt vmcnt(0)" ::: "memory");
  __builtin_amdgcn_sched_barrier(0);
  __builtin_amdgcn_s_barrier();

  bf16x8 qf[2][2];
#pragma unroll
  for (int m = 0; m < 2; m++) {
    const int row = wave * 32 + m * 16 + l16;
    const int qm = mask[(size_t)b * S + qt + row];   // query-axis mask (matches ref)
#pragma unroll
    for (int ks = 0; ks < 2; ks++) {
      bf16x8 v = *(const bf16x8*)&sQ[row * 64 + (((ks * 4 + hi) ^ swz) * 8)];
      u32x4 u = __builtin_bit_cast(u32x4, v);
#pragma unroll
      for (int c = 0; c < 4; c++) u[c] = qm ? u[c] : 0u;
      qf[m][ks] = __builtin_bit_cast(bf16x8, u);
    }
  }
  __syncthreads();   // frag reads done before K staging overwrites sK

  // ---- per-thread staging source pointers (advance by constants per tile)
  const unsigned short* pK0; const unsigned short* pK1;
  const unsigned short* pV0; const unsigned short* pV1;
  {
    int row = tid >> 3, c = tid & 7;
    int cs = (c ^ (row & 7)) * 8;
    pK0 = Kb + (size_t)row * H + cs;
    pK1 = Kb + (size_t)(64 + row) * H + cs;
    int d = tid >> 4, kvc = tid & 15;
    int sg = ((kvc ^ d) & 7) | (kvc & 8);
    pV0 = Vb + (size_t)d * 2048 + sg * 8;
    pV1 = Vb + (size_t)(32 + d) * 2048 + sg * 8;
  }

  // ---- stage first K/V tile into buffer 0
  load_lds16(pK0, &sK[0][(wave * 64) * 8]);
  load_lds16(pK1, &sK[0][(512 + wave * 64) * 8]);
  load_lds16(pV0, &sV[0][(wave * 64) * 8]);
  load_lds16(pV1, &sV[0][(512 + wave * 64) * 8]);
  pK0 += 128 * H; pK1 += 128 * H; pV0 += 128; pV1 += 128;

  float lsum[2] = {0.f, 0.f};
  f32x4 oacc[2][4] = {};

  for (int t = 0; t < 16; t++) {
    const int cur = t & 1;
    // issue next-tile staging, then wait only for the CURRENT tile (counted vmcnt)
    if (t < 15) {
      unsigned short* nK = sK[cur ^ 1];
      unsigned short* nV = sV[cur ^ 1];
      load_lds16(pK0, &nK[(wave * 64) * 8]);
      load_lds16(pK1, &nK[(512 + wave * 64) * 8]);
      load_lds16(pV0, &nV[(wave * 64) * 8]);
      load_lds16(pV1, &nV[(512 + wave * 64) * 8]);
      pK0 += 128 * H; pK1 += 128 * H; pV0 += 128; pV1 += 128;
      asm volatile("s_waitcnt vmcnt(4)" ::: "memory");
    } else {
      asm volatile("s_waitcnt vmcnt(0)" ::: "memory");
    }
    __builtin_amdgcn_sched_barrier(0);
    __builtin_amdgcn_s_barrier();

    const unsigned short* kb = sK[cur];
    const unsigned short* vb = sV[cur];

    // process the 128-kv tile in two 64-kv halves (bounds sf register pressure)
#pragma unroll
    for (int hf = 0; hf < 2; hf++) {
      // ---- QK^T swapped: sf[m][jj] (log2 domain); lane: q=l16, kv=(hf*4+jj)*16+hi*4+r
      f32x4 sf[2][4];
      __builtin_amdgcn_s_setprio(1);
#pragma unroll
      for (int jj = 0; jj < 4; jj++) {
        const int ro = (hf * 4 + jj) * 1024;
        bf16x8 kf0 = *(const bf16x8*)&kb[ro + kinv0];
        bf16x8 kf1 = *(const bf16x8*)&kb[ro + kinv1];
#pragma unroll
        for (int m = 0; m < 2; m++) {
          f32x4 acc = {};
          acc = __builtin_amdgcn_mfma_f32_16x16x32_bf16(kf0, qf[m][0], acc, 0, 0, 0);
          acc = __builtin_amdgcn_mfma_f32_16x16x32_bf16(kf1, qf[m][1], acc, 0, 0, 0);
          sf[m][jj] = acc;
        }
      }
      __builtin_amdgcn_s_setprio(0);

      // ---- constant-max softmax: P = exp2(s - 16)
#pragma unroll
      for (int m = 0; m < 2; m++) {
#pragma unroll
        for (int jj = 0; jj < 4; jj++)
#pragma unroll
          for (int r = 0; r < 4; r++)
            sf[m][jj][r] = fexp2(sf[m][jj][r] - 16.0f);
        f32x4 c4 = (sf[m][0] + sf[m][1]) + (sf[m][2] + sf[m][3]);
        lsum[m] += (c4[0] + c4[1]) + (c4[2] + c4[3]);
      }

      // ---- P repack (permlane) + PV per 32-kv window; V-frag shared across m
#pragma unroll
      for (int w2 = 0; w2 < 2; w2++) {
        bf16x8 af0 = repack_af(sf[0][2 * w2], sf[0][2 * w2 + 1]);
        bf16x8 af1 = repack_af(sf[1][2 * w2], sf[1][2 * w2 + 1]);
        const int gw = hf * 2 + w2;
        const int vo = ((gw & 2) ? 64 : 0) + ((gw & 1) ? vinv1 : vinv0);
        __builtin_amdgcn_s_setprio(1);
#pragma unroll
        for (int n = 0; n < 4; n++) {
          bf16x8 vf = *(const bf16x8*)&vb[n * 2048 + vo];
          oacc[0][n] = __builtin_amdgcn_mfma_f32_16x16x32_bf16(af0, vf, oacc[0][n], 0, 0, 0);
          oacc[1][n] = __builtin_amdgcn_mfma_f32_16x16x32_bf16(af1, vf, oacc[1][n], 0, 0, 0);
        }
        __builtin_amdgcn_s_setprio(0);
      }
    }
    __builtin_amdgcn_sched_barrier(0);
    __builtin_amdgcn_s_barrier();
  }

  // ---- epilogue: reduce denominators once, then O / l -> Yb (bf16)
#pragma unroll
  for (int m = 0; m < 2; m++) {
    lsum[m] += __shfl_xor(lsum[m], 16);
    lsum[m] += __shfl_xor(lsum[m], 32);
  }
#pragma unroll
  for (int m = 0; m < 2; m++) {
    float lr[4];
#pragma unroll
    for (int r = 0; r < 4; r++) lr[r] = 1.0f / __shfl(lsum[m], hi * 4 + r);
#pragma unroll
    for (int n = 0; n < 4; n++)
#pragma unroll
      for (int r = 0; r < 4; r++) {
        int row = qt + wave * 32 + m * 16 + hi * 4 + r;
        int col = n * 16 + l16;
        Yb[((size_t)b * S + row) * H + h * 64 + col] = f2bf(oacc[m][n][r] * lr[r]);
      }
  }
}

// ---------------------------------------------------------------- launch
extern "C" void kernel_launch(void* const* d_in, const int* in_sizes, int n_in,
                              void* d_out, int out_size, void* d_ws, size_t ws_size,
                              hipStream_t stream)
{
  const float* q  = (const float*)d_in[0];
  const float* k  = (const float*)d_in[1];
  const float* v  = (const float*)d_in[2];
  const int*  mask = (const int*)d_in[3];
  const float* Wq = (const float*)d_in[4];
  const float* bq = (const float*)d_in[5];
  const float* Wk = (const float*)d_in[6];
  const float* bk = (const float*)d_in[7];
  const float* Wv = (const float*)d_in[8];
  const float* bv = (const float*)d_in[9];
  const float* Wo = (const float*)d_in[10];
  const float* bo = (const float*)d_in[11];

  unsigned short* ws  = (unsigned short*)d_ws;
  unsigned short* wqb = ws;                 //  0..1 EL (bf16 weights)
  unsigned short* wkb = ws + 1 * EL;        //  1..2
  unsigned short* wvb = ws + 2 * EL;        //  2..3
  unsigned short* wob = ws + 3 * EL;        //  3..4
  unsigned short* Qp  = ws + 4 * EL;        //  4..8
  unsigned short* Kp  = ws + 8 * EL;        //  8..12
  unsigned short* Vt  = ws + 12 * EL;       // 12..16  [32][64][2048] bf16
  unsigned short* Yb  = ws + 16 * EL;       // 16..20

  convert_w<<<1024, 256, 0, stream>>>(Wq, Wk, Wv, Wo, ws);
  qkv_gemm<<<dim3(8, 32, 3), 256, 0, stream>>>(q, k, v, wqb, wkb, wvb,
                                               bq, bk, bv, Qp, Kp, Vt);
  attn_kernel<<<dim3(8, 16, 2), 512, 0, stream>>>(Qp, Kp, Vt, mask, Yb);
  out_gemm<<<dim3(16, 32), 256, 0, stream>>>(Yb, wob, bo, (float*)d_out);
}

// Round 11
// 123.296 us; speedup vs baseline: 1.1523x; 1.1523x over previous
//
#include <hip/hip_runtime.h>
#include <hip/hip_bf16.h>
#include <cstdint>

#define EL 1048576ull   // 1Mi elements

typedef __bf16 bf16_t;
typedef bf16_t bf16x8 __attribute__((ext_vector_type(8)));
typedef float  f32x4  __attribute__((ext_vector_type(4)));
typedef unsigned int u32x2 __attribute__((ext_vector_type(2)));
typedef unsigned int u32x4 __attribute__((ext_vector_type(4)));

__device__ __forceinline__ unsigned short f2bf(float f) {
  unsigned int u = __builtin_bit_cast(unsigned int, f);
  u += 0x7FFFu + ((u >> 16) & 1u);   // RNE
  return (unsigned short)(u >> 16);
}

// pack 2 f32 -> 2 bf16 in one u32 (lo -> low half), RNE; proven round 5
__device__ __forceinline__ unsigned int cvtpk(float lo, float hi2) {
  unsigned int r;
  asm("v_cvt_pk_bf16_f32 %0, %1, %2" : "=v"(r) : "v"(lo), "v"(hi2));
  return r;
}

__device__ __forceinline__ float fexp2(float x) {
#if __has_builtin(__builtin_amdgcn_exp2f)
  return __builtin_amdgcn_exp2f(x);
#else
  return exp2f(x);
#endif
}

typedef __attribute__((address_space(1))) void as1_void;
typedef __attribute__((address_space(3))) void as3_void;
__device__ __forceinline__ void load_lds16(const void* g, void* l) {
  __builtin_amdgcn_global_load_lds((as1_void*)g, (as3_void*)l, 16, 0, 0);
}

// P repack via permlane swaps (VALU, no LDS pipe); proven round 6
__device__ __forceinline__ bf16x8 repack_af(const f32x4 s0v, const f32x4 s1v) {
  unsigned int c00 = cvtpk(s0v[0], s0v[1]);
  unsigned int c01 = cvtpk(s0v[2], s0v[3]);
  unsigned int c10 = cvtpk(s1v[0], s1v[1]);
  unsigned int c11 = cvtpk(s1v[2], s1v[3]);
  asm("v_permlane32_swap_b32 %0, %1" : "+v"(c00), "+v"(c10));
  asm("v_permlane16_swap_b32 %0, %1" : "+v"(c00), "+v"(c10));
  asm("v_permlane32_swap_b32 %0, %1" : "+v"(c01), "+v"(c11));
  asm("v_permlane16_swap_b32 %0, %1" : "+v"(c01), "+v"(c11));
  u32x4 wd; wd[0] = c00; wd[1] = c01; wd[2] = c10; wd[3] = c11;
  return __builtin_bit_cast(bf16x8, wd);
}

// ---------------------------------------------------------------- convert
__global__ __launch_bounds__(256) void convert_all(
    const float* __restrict__ q, const float* __restrict__ k, const float* __restrict__ v,
    const float* __restrict__ wq, const float* __restrict__ wk,
    const float* __restrict__ wv, const float* __restrict__ wo,
    unsigned short* __restrict__ ws)
{
  const size_t total_v4 = 4 * EL; // 16M elems / 4
  for (size_t v4 = (size_t)blockIdx.x * blockDim.x + threadIdx.x; v4 < total_v4;
       v4 += (size_t)gridDim.x * blockDim.x) {
    size_t e = v4 * 4;
    unsigned seg = (unsigned)(e >> 20);
    const float* s; size_t base;
    if      (seg < 4)   { s = q;  base = 0; }
    else if (seg < 8)   { s = k;  base = 4*EL; }
    else if (seg < 12)  { s = v;  base = 8*EL; }
    else if (seg == 12) { s = wq; base = 12*EL; }
    else if (seg == 13) { s = wk; base = 13*EL; }
    else if (seg == 14) { s = wv; base = 14*EL; }
    else                { s = wo; base = 15*EL; }
    const float4 f = *(const float4*)(s + (e - base));
    ushort4 o;
    o.x = f2bf(f.x); o.y = f2bf(f.y); o.z = f2bf(f.z); o.w = f2bf(f.w);
    *(ushort4*)(ws + e) = o;
  }
}

// ---------------------------------------------------------------- GEMM main loop (acc += A * B^T)
template <int BM, int BN, int WM, int WN>
__device__ __forceinline__ void gemm_bt_main(
    const unsigned short* __restrict__ A,
    const unsigned short* __restrict__ B,
    f32x4 (&acc)[BM / WM / 16][BN / WN / 16])
{
  constexpr int K = 1024, BK = 64;
  constexpr int AM = BM / WM / 16, AN = BN / WN / 16;
  __shared__ __align__(16) unsigned short sA[BM * BK];
  __shared__ __align__(16) unsigned short sB[BN * BK];
  const int tid  = threadIdx.x;
  const int wave = tid >> 6, lane = tid & 63;
  const int wm = wave / WN, wn = wave % WN;
  const int tm = blockIdx.y * BM, tn = blockIdx.x * BN;
  const int l16 = lane & 15, hi = lane >> 4, swz = l16 & 7;

  for (int k0 = 0; k0 < K; k0 += BK) {
    __syncthreads();
#pragma unroll
    for (int i = 0; i < BM * 8 / 256; i++) {
      int p = i * 256 + tid;
      int row = p >> 3, c = p & 7;
      load_lds16(A + (size_t)(tm + row) * K + k0 + ((c ^ (row & 7)) * 8),
                 &sA[(i * 256 + wave * 64) * 8]);
    }
#pragma unroll
    for (int i = 0; i < BN * 8 / 256; i++) {
      int p = i * 256 + tid;
      int row = p >> 3, c = p & 7;
      load_lds16(B + (size_t)(tn + row) * K + k0 + ((c ^ (row & 7)) * 8),
                 &sB[(i * 256 + wave * 64) * 8]);
    }
    __syncthreads();

#pragma unroll
    for (int kk = 0; kk < 2; kk++) {
      bf16x8 af[AM], bfr[AN];
#pragma unroll
      for (int i = 0; i < AM; i++) {
        int row = wm * (BM / WM) + i * 16 + l16;
        af[i] = *(const bf16x8*)&sA[row * BK + (((kk * 4 + hi) ^ swz) * 8)];
      }
#pragma unroll
      for (int j = 0; j < AN; j++) {
        int row = wn * (BN / WN) + j * 16 + l16;
        bfr[j] = *(const bf16x8*)&sB[row * BK + (((kk * 4 + hi) ^ swz) * 8)];
      }
#pragma unroll
      for (int i = 0; i < AM; i++)
#pragma unroll
        for (int j = 0; j < AN; j++)
          acc[i][j] = __builtin_amdgcn_mfma_f32_16x16x32_bf16(af[i], bfr[j], acc[i][j], 0, 0, 0);
    }
  }
}

// ---------------------------------------------------------------- QKV projections
__global__ __launch_bounds__(256, 3) void qkv_gemm(
    const unsigned short* qb, const unsigned short* kb, const unsigned short* vb,
    const unsigned short* wqb, const unsigned short* wkb, const unsigned short* wvb,
    const float* bq, const float* bk, const float* bv,
    unsigned short* Qp, unsigned short* Kp, unsigned short* Vt)
{
  const unsigned short* A; const unsigned short* B; const float* bias;
  if (blockIdx.z == 0)      { A = qb; B = wqb; bias = bq; }
  else if (blockIdx.z == 1) { A = kb; B = wkb; bias = bk; }
  else                      { A = vb; B = wvb; bias = bv; }

  f32x4 acc[4][4] = {};
  gemm_bt_main<128, 128, 2, 2>(A, B, acc);

  const int tid = threadIdx.x, wave = tid >> 6, lane = tid & 63;
  const int wm = wave >> 1, wn = wave & 1;
  const int tm = blockIdx.y * 128, tn = blockIdx.x * 128;
  const int l16 = lane & 15, hi = lane >> 4;

  if (blockIdx.z < 2) {
    unsigned short* C = (blockIdx.z == 0) ? Qp : Kp;
    const float scale = (blockIdx.z == 0) ? 0.18033688011112042f : 1.0f; // 0.125*log2(e)
#pragma unroll
    for (int i = 0; i < 4; i++) {
      int row0 = tm + wm * 64 + i * 16 + hi * 4;
#pragma unroll
      for (int j = 0; j < 4; j++) {
        int col = tn + wn * 64 + j * 16 + l16;
        float bv2 = bias[col];
#pragma unroll
        for (int r = 0; r < 4; r++)
          C[(size_t)(row0 + r) * 1024 + col] = f2bf((acc[i][j][r] + bv2) * scale);
      }
    }
  } else {
    // transposed V write: lane's 4 rows are 4 consecutive s -> one 8B store
#pragma unroll
    for (int i = 0; i < 4; i++) {
      int row0 = tm + wm * 64 + i * 16 + hi * 4;
      int bb = row0 >> 11, s = row0 & 2047;
#pragma unroll
      for (int j = 0; j < 4; j++) {
        int col = tn + wn * 64 + j * 16 + l16;
        int hh = col >> 6, d = col & 63;
        float bv2 = bias[col];
        u32x2 w;
        w[0] = cvtpk(acc[i][j][0] + bv2, acc[i][j][1] + bv2);
        w[1] = cvtpk(acc[i][j][2] + bv2, acc[i][j][3] + bv2);
        *(u32x2*)&Vt[((size_t)(bb * 16 + hh) * 64 + d) * 2048 + s] = w;
      }
    }
  }
}

__global__ __launch_bounds__(256, 2) void out_gemm(
    const unsigned short* Yb, const unsigned short* wob, const float* bo, float* out)
{
  f32x4 acc[2][4] = {};
  gemm_bt_main<128, 64, 4, 1>(Yb, wob, acc);

  const int tid = threadIdx.x, wave = tid >> 6, lane = tid & 63;
  const int tm = blockIdx.y * 128, tn = blockIdx.x * 64;
  const int l16 = lane & 15, hi = lane >> 4;
#pragma unroll
  for (int i = 0; i < 2; i++) {
    int row0 = tm + wave * 32 + i * 16 + hi * 4;
#pragma unroll
    for (int j = 0; j < 4; j++) {
      int col = tn + j * 16 + l16;
      float bv2 = bo[col];
#pragma unroll
      for (int r = 0; r < 4; r++)
        out[(size_t)(row0 + r) * 1024 + col] = acc[i][j][r] + bv2;
    }
  }
}

// ---------------------------------------------------------------- flash attention (q-split)
// 4 waves x 32 q-rows = 128 q per block; grid 16x16x2 = 512 blocks = 2 blocks/CU
// (doubles occupancy vs r7 with NO combine pass; K/V re-reads stay LLC-resident).
// Swapped QK^T (log2 domain, scale folded into Q projection), constant-max softmax
// (P = exp2(s-16), shift-invariant), permlane P repack, double-buffered K/V staging
// with counted vmcnt + pointer-marched sources, setprio on MFMA clusters.
__global__ __launch_bounds__(256, 2) void attn_kernel(
    const unsigned short* __restrict__ Qp, const unsigned short* __restrict__ Kp,
    const unsigned short* __restrict__ Vt, const int* __restrict__ mask,
    unsigned short* __restrict__ Yb)
{
  constexpr int S = 2048, H = 1024;
  __shared__ __align__(16) unsigned short sK[2][128 * 64];  // K tiles (buf1 also Q staging)
  __shared__ __align__(16) unsigned short sV[2][64 * 128];  // V^T tiles [d][kv]

  const int tid = threadIdx.x, wave = tid >> 6, lane = tid & 63;
  const int l16 = lane & 15, hi = lane >> 4, swz = l16 & 7;
  const int qt = blockIdx.x * 128;
  const int h = blockIdx.y, b = blockIdx.z, bh = b * 16 + h;
  const unsigned short* Qb = Qp + (size_t)b * S * H + (size_t)h * 64;
  const unsigned short* Kb = Kp + (size_t)b * S * H + (size_t)h * 64;
  const unsigned short* Vb = Vt + (size_t)bh * 64 * 2048;

  // loop-invariant LDS read offsets (shorts)
  const int kinv0 = l16 * 64 + ((hi ^ swz) * 8);
  const int kinv1 = l16 * 64 + (((4 + hi) ^ swz) * 8);
  const int vinv0 = l16 * 128 + ((hi ^ swz) * 8);
  const int vinv1 = l16 * 128 + (((4 + hi) ^ swz) * 8);

  // ---- stage Q (128x64 = 16KB) into sK[1] while K0/V0 prefetch into buf 0
#pragma unroll
  for (int i = 0; i < 4; i++) {
    int p = i * 256 + tid, row = p >> 3, c = p & 7;
    load_lds16(Qb + (size_t)(qt + row) * H + ((c ^ (row & 7)) * 8),
               &sK[1][(i * 256 + wave * 64) * 8]);
  }
  // per-thread staging source pointers (advance by constants per tile)
  const unsigned short* pK[4]; const unsigned short* pV[4];
#pragma unroll
  for (int j = 0; j < 4; j++) {
    int g = j * 256 + tid;
    int row = g >> 3, c = g & 7;
    pK[j] = Kb + (size_t)row * H + ((c ^ (row & 7)) * 8);
    int d = g >> 4, kvc = g & 15;
    int sg = ((kvc ^ d) & 7) | (kvc & 8);
    pV[j] = Vb + (size_t)d * 2048 + sg * 8;
  }
#pragma unroll
  for (int j = 0; j < 4; j++)
    load_lds16(pK[j], &sK[0][(j * 256 + wave * 64) * 8]);
#pragma unroll
  for (int j = 0; j < 4; j++)
    load_lds16(pV[j], &sV[0][(j * 256 + wave * 64) * 8]);
#pragma unroll
  for (int j = 0; j < 4; j++) { pK[j] += 128 * H; pV[j] += 128; }

  asm volatile("s_waitcnt vmcnt(8)" ::: "memory");  // Q landed; K0/V0 still in flight
  __builtin_amdgcn_sched_barrier(0);
  __builtin_amdgcn_s_barrier();

  bf16x8 qf[2][2];
#pragma unroll
  for (int m = 0; m < 2; m++) {
    const int row = wave * 32 + m * 16 + l16;
    const int qm = mask[(size_t)b * S + qt + row];   // query-axis mask (matches ref)
#pragma unroll
    for (int ks = 0; ks < 2; ks++) {
      bf16x8 v = *(const bf16x8*)&sK[1][row * 64 + (((ks * 4 + hi) ^ swz) * 8)];
      u32x4 u = __builtin_bit_cast(u32x4, v);
#pragma unroll
      for (int c = 0; c < 4; c++) u[c] = qm ? u[c] : 0u;
      qf[m][ks] = __builtin_bit_cast(bf16x8, u);
    }
  }
  // all waves' Q-frag reads must land before t=0 stages into sK[1];
  // drain LDS reads only (K0/V0 global->LDS stay in flight on vmcnt)
  asm volatile("s_waitcnt lgkmcnt(0)" ::: "memory");
  __builtin_amdgcn_sched_barrier(0);
  __builtin_amdgcn_s_barrier();

  float lsum[2] = {0.f, 0.f};
  f32x4 oacc[2][4] = {};

  for (int t = 0; t < 16; t++) {
    const int cur = t & 1;
    // issue next-tile staging, then wait only for the CURRENT tile (counted vmcnt)
    if (t < 15) {
      unsigned short* nK = sK[cur ^ 1];
      unsigned short* nV = sV[cur ^ 1];
#pragma unroll
      for (int j = 0; j < 4; j++)
        load_lds16(pK[j], &nK[(j * 256 + wave * 64) * 8]);
#pragma unroll
      for (int j = 0; j < 4; j++)
        load_lds16(pV[j], &nV[(j * 256 + wave * 64) * 8]);
#pragma unroll
      for (int j = 0; j < 4; j++) { pK[j] += 128 * H; pV[j] += 128; }
      asm volatile("s_waitcnt vmcnt(8)" ::: "memory");
    } else {
      asm volatile("s_waitcnt vmcnt(0)" ::: "memory");
    }
    __builtin_amdgcn_sched_barrier(0);
    __builtin_amdgcn_s_barrier();

    const unsigned short* kb = sK[cur];
    const unsigned short* vb = sV[cur];

    // process the 128-kv tile in two 64-kv halves (bounds sf register pressure)
#pragma unroll
    for (int hf = 0; hf < 2; hf++) {
      // ---- QK^T swapped: sf[m][jj] (log2 domain); lane: q=l16, kv=(hf*4+jj)*16+hi*4+r
      f32x4 sf[2][4];
      __builtin_amdgcn_s_setprio(1);
#pragma unroll
      for (int jj = 0; jj < 4; jj++) {
        const int ro = (hf * 4 + jj) * 1024;
        bf16x8 kf0 = *(const bf16x8*)&kb[ro + kinv0];
        bf16x8 kf1 = *(const bf16x8*)&kb[ro + kinv1];
#pragma unroll
        for (int m = 0; m < 2; m++) {
          f32x4 acc = {};
          acc = __builtin_amdgcn_mfma_f32_16x16x32_bf16(kf0, qf[m][0], acc, 0, 0, 0);
          acc = __builtin_amdgcn_mfma_f32_16x16x32_bf16(kf1, qf[m][1], acc, 0, 0, 0);
          sf[m][jj] = acc;
        }
      }
      __builtin_amdgcn_s_setprio(0);

      // ---- constant-max softmax: P = exp2(s - 16)
#pragma unroll
      for (int m = 0; m < 2; m++) {
#pragma unroll
        for (int jj = 0; jj < 4; jj++)
#pragma unroll
          for (int r = 0; r < 4; r++)
            sf[m][jj][r] = fexp2(sf[m][jj][r] - 16.0f);
        f32x4 c4 = (sf[m][0] + sf[m][1]) + (sf[m][2] + sf[m][3]);
        lsum[m] += (c4[0] + c4[1]) + (c4[2] + c4[3]);
      }

      // ---- P repack (permlane) + PV per 32-kv window; V-frag shared across m
#pragma unroll
      for (int w2 = 0; w2 < 2; w2++) {
        bf16x8 af0 = repack_af(sf[0][2 * w2], sf[0][2 * w2 + 1]);
        bf16x8 af1 = repack_af(sf[1][2 * w2], sf[1][2 * w2 + 1]);
        const int gw = hf * 2 + w2;
        const int vo = ((gw & 2) ? 64 : 0) + ((gw & 1) ? vinv1 : vinv0);
        __builtin_amdgcn_s_setprio(1);
#pragma unroll
        for (int n = 0; n < 4; n++) {
          bf16x8 vf = *(const bf16x8*)&vb[n * 2048 + vo];
          oacc[0][n] = __builtin_amdgcn_mfma_f32_16x16x32_bf16(af0, vf, oacc[0][n], 0, 0, 0);
          oacc[1][n] = __builtin_amdgcn_mfma_f32_16x16x32_bf16(af1, vf, oacc[1][n], 0, 0, 0);
        }
        __builtin_amdgcn_s_setprio(0);
      }
    }
    __builtin_amdgcn_sched_barrier(0);
    __builtin_amdgcn_s_barrier();
  }

  // ---- epilogue: reduce denominators once, then O / l -> Yb (bf16)
#pragma unroll
  for (int m = 0; m < 2; m++) {
    lsum[m] += __shfl_xor(lsum[m], 16);
    lsum[m] += __shfl_xor(lsum[m], 32);
  }
#pragma unroll
  for (int m = 0; m < 2; m++) {
    float lr[4];
#pragma unroll
    for (int r = 0; r < 4; r++) lr[r] = 1.0f / __shfl(lsum[m], hi * 4 + r);
#pragma unroll
    for (int n = 0; n < 4; n++)
#pragma unroll
      for (int r = 0; r < 4; r++) {
        int row = qt + wave * 32 + m * 16 + hi * 4 + r;
        int col = n * 16 + l16;
        Yb[((size_t)b * S + row) * H + h * 64 + col] = f2bf(oacc[m][n][r] * lr[r]);
      }
  }
}

// ---------------------------------------------------------------- launch
extern "C" void kernel_launch(void* const* d_in, const int* in_sizes, int n_in,
                              void* d_out, int out_size, void* d_ws, size_t ws_size,
                              hipStream_t stream)
{
  const float* q  = (const float*)d_in[0];
  const float* k  = (const float*)d_in[1];
  const float* v  = (const float*)d_in[2];
  const int*  mask = (const int*)d_in[3];
  const float* Wq = (const float*)d_in[4];
  const float* bq = (const float*)d_in[5];
  const float* Wk = (const float*)d_in[6];
  const float* bk = (const float*)d_in[7];
  const float* Wv = (const float*)d_in[8];
  const float* bv = (const float*)d_in[9];
  const float* Wo = (const float*)d_in[10];
  const float* bo = (const float*)d_in[11];

  unsigned short* ws  = (unsigned short*)d_ws;
  unsigned short* qb  = ws;                 //  0..4  EL
  unsigned short* kb  = ws + 4 * EL;        //  4..8
  unsigned short* vb  = ws + 8 * EL;        //  8..12
  unsigned short* wqb = ws + 12 * EL;       // 12..13
  unsigned short* wkb = ws + 13 * EL;       // 13..14
  unsigned short* wvb = ws + 14 * EL;       // 14..15
  unsigned short* wob = ws + 15 * EL;       // 15..16
  unsigned short* Qp  = ws + 16 * EL;       // 16..20
  unsigned short* Kp  = ws + 20 * EL;       // 20..24
  unsigned short* Vt  = ws + 24 * EL;       // 24..28  [32][64][2048] bf16
  unsigned short* Yb  = ws + 28 * EL;       // 28..32

  convert_all<<<2048, 256, 0, stream>>>(q, k, v, Wq, Wk, Wv, Wo, ws);
  qkv_gemm<<<dim3(8, 32, 3), 256, 0, stream>>>(qb, kb, vb, wqb, wkb, wvb,
                                               bq, bk, bv, Qp, Kp, Vt);
  attn_kernel<<<dim3(16, 16, 2), 256, 0, stream>>>(Qp, Kp, Vt, mask, Yb);
  out_gemm<<<dim3(16, 32), 256, 0, stream>>>(Yb, wob, bo, (float*)d_out);
}

// Round 12
// 109.650 us; speedup vs baseline: 1.2957x; 1.1244x over previous
//
#include <hip/hip_runtime.h>
#include <hip/hip_bf16.h>
#include <cstdint>

#define EL 1048576ull   // 1Mi elements

typedef __bf16 bf16_t;
typedef bf16_t bf16x8 __attribute__((ext_vector_type(8)));
typedef float  f32x4  __attribute__((ext_vector_type(4)));
typedef unsigned int u32x2 __attribute__((ext_vector_type(2)));
typedef unsigned int u32x4 __attribute__((ext_vector_type(4)));

__device__ __forceinline__ unsigned short f2bf(float f) {
  unsigned int u = __builtin_bit_cast(unsigned int, f);
  u += 0x7FFFu + ((u >> 16) & 1u);   // RNE
  return (unsigned short)(u >> 16);
}

// pack 2 f32 -> 2 bf16 in one u32 (lo -> low half), RNE; proven round 5
__device__ __forceinline__ unsigned int cvtpk(float lo, float hi2) {
  unsigned int r;
  asm("v_cvt_pk_bf16_f32 %0, %1, %2" : "=v"(r) : "v"(lo), "v"(hi2));
  return r;
}

__device__ __forceinline__ float fexp2(float x) {
#if __has_builtin(__builtin_amdgcn_exp2f)
  return __builtin_amdgcn_exp2f(x);
#else
  return exp2f(x);
#endif
}

typedef __attribute__((address_space(1))) void as1_void;
typedef __attribute__((address_space(3))) void as3_void;
__device__ __forceinline__ void load_lds16(const void* g, void* l) {
  __builtin_amdgcn_global_load_lds((as1_void*)g, (as3_void*)l, 16, 0, 0);
}

// P repack via permlane swaps (VALU, no LDS pipe); proven round 6
__device__ __forceinline__ bf16x8 repack_af(const f32x4 s0v, const f32x4 s1v) {
  unsigned int c00 = cvtpk(s0v[0], s0v[1]);
  unsigned int c01 = cvtpk(s0v[2], s0v[3]);
  unsigned int c10 = cvtpk(s1v[0], s1v[1]);
  unsigned int c11 = cvtpk(s1v[2], s1v[3]);
  asm("v_permlane32_swap_b32 %0, %1" : "+v"(c00), "+v"(c10));
  asm("v_permlane16_swap_b32 %0, %1" : "+v"(c00), "+v"(c10));
  asm("v_permlane32_swap_b32 %0, %1" : "+v"(c01), "+v"(c11));
  asm("v_permlane16_swap_b32 %0, %1" : "+v"(c01), "+v"(c11));
  u32x4 wd; wd[0] = c00; wd[1] = c01; wd[2] = c10; wd[3] = c11;
  return __builtin_bit_cast(bf16x8, wd);
}

// ---------------------------------------------------------------- convert weights only
// wq/wk/wv/wo (f32, 1M elems each) -> ws[0..4EL) bf16. q/k/v are converted
// in-flight inside qkv_gemm (read-once; panel-clustered XCD mapping keeps the
// f32 re-reads in one XCD's L2 -> each panel fetched from HBM once).
__global__ __launch_bounds__(256) void convert_w(
    const float* __restrict__ wq, const float* __restrict__ wk,
    const float* __restrict__ wv, const float* __restrict__ wo,
    unsigned short* __restrict__ ws)
{
  for (size_t v4 = (size_t)blockIdx.x * blockDim.x + threadIdx.x; v4 < EL;
       v4 += (size_t)gridDim.x * blockDim.x) {
    size_t e = v4 * 4;
    unsigned seg = (unsigned)(e >> 20);
    const float* s = (seg == 0) ? wq : (seg == 1) ? wk : (seg == 2) ? wv : wo;
    const float4 f = *(const float4*)(s + (e & (EL - 1)));
    ushort4 o;
    o.x = f2bf(f.x); o.y = f2bf(f.y); o.z = f2bf(f.z); o.w = f2bf(f.w);
    *(ushort4*)(ws + e) = o;
  }
}

// ---------------------------------------------------------------- GEMM main loop (acc += A * B^T)
// B: [1024][1024] bf16 (row n holds B[n][k]). A: bf16 [M][1024], or f32 [M][1024]
// with in-flight bf16 conversion (AF32). XOR-swizzled LDS, identical layout both paths.
template <int BM, int BN, int WM, int WN, bool AF32>
__device__ __forceinline__ void gemm_bt_main(
    const void* __restrict__ A,
    const unsigned short* __restrict__ B,
    f32x4 (&acc)[BM / WM / 16][BN / WN / 16],
    const int tm, const int tn)
{
  constexpr int K = 1024, BK = 64;
  constexpr int AM = BM / WM / 16, AN = BN / WN / 16;
  __shared__ __align__(16) unsigned short sA[BM * BK];
  __shared__ __align__(16) unsigned short sB[BN * BK];
  const int tid  = threadIdx.x;
  const int wave = tid >> 6, lane = tid & 63;
  const int wm = wave / WN, wn = wave % WN;
  const int l16 = lane & 15, hi = lane >> 4, swz = l16 & 7;

  for (int k0 = 0; k0 < K; k0 += BK) {
    __syncthreads();
    if constexpr (AF32) {
      const float* Af = (const float*)A;
#pragma unroll
      for (int i = 0; i < BM * 8 / 256; i++) {
        int p = i * 256 + tid;
        int row = p >> 3, c = p & 7;
        const float* src = Af + (size_t)(tm + row) * K + k0 + ((c ^ (row & 7)) * 8);
        float4 f0 = *(const float4*)src;
        float4 f1 = *(const float4*)(src + 4);
        u32x4 w;
        w[0] = cvtpk(f0.x, f0.y); w[1] = cvtpk(f0.z, f0.w);
        w[2] = cvtpk(f1.x, f1.y); w[3] = cvtpk(f1.z, f1.w);
        *(u32x4*)&sA[(size_t)p * 8] = w;
      }
    } else {
      const unsigned short* Ab = (const unsigned short*)A;
#pragma unroll
      for (int i = 0; i < BM * 8 / 256; i++) {
        int p = i * 256 + tid;
        int row = p >> 3, c = p & 7;
        load_lds16(Ab + (size_t)(tm + row) * K + k0 + ((c ^ (row & 7)) * 8),
                   &sA[(i * 256 + wave * 64) * 8]);
      }
    }
#pragma unroll
    for (int i = 0; i < BN * 8 / 256; i++) {
      int p = i * 256 + tid;
      int row = p >> 3, c = p & 7;
      load_lds16(B + (size_t)(tn + row) * K + k0 + ((c ^ (row & 7)) * 8),
                 &sB[(i * 256 + wave * 64) * 8]);
    }
    __syncthreads();

#pragma unroll
    for (int kk = 0; kk < 2; kk++) {
      bf16x8 af[AM], bfr[AN];
#pragma unroll
      for (int i = 0; i < AM; i++) {
        int row = wm * (BM / WM) + i * 16 + l16;
        af[i] = *(const bf16x8*)&sA[row * BK + (((kk * 4 + hi) ^ swz) * 8)];
      }
#pragma unroll
      for (int j = 0; j < AN; j++) {
        int row = wn * (BN / WN) + j * 16 + l16;
        bfr[j] = *(const bf16x8*)&sB[row * BK + (((kk * 4 + hi) ^ swz) * 8)];
      }
#pragma unroll
      for (int i = 0; i < AM; i++)
#pragma unroll
        for (int j = 0; j < AN; j++)
          acc[i][j] = __builtin_amdgcn_mfma_f32_16x16x32_bf16(af[i], bfr[j], acc[i][j], 0, 0, 0);
    }
  }
}

// ---------------------------------------------------------------- QKV projections (A = f32 inputs)
// Grid (8, 32, 3). XCD = dispatch_linear % 8 = blockIdx.x. Remap so the 8 N-tiles
// sharing an A-panel all carry the same blockIdx.x -> same XCD -> A f32 panel is
// fetched from HBM once and re-read from that XCD's L2.
__global__ __launch_bounds__(256, 3) void qkv_gemm(
    const float* q, const float* k, const float* v,
    const unsigned short* wqb, const unsigned short* wkb, const unsigned short* wvb,
    const float* bq, const float* bk, const float* bv,
    unsigned short* Qp, unsigned short* Kp, unsigned short* Vt)
{
  const float* A; const unsigned short* B; const float* bias;
  if (blockIdx.z == 0)      { A = q; B = wqb; bias = bq; }
  else if (blockIdx.z == 1) { A = k; B = wkb; bias = bk; }
  else                      { A = v; B = wvb; bias = bv; }

  const int xd = blockIdx.x, yd = blockIdx.y;
  const int mt = xd + 8 * (yd & 3);    // A-panel id 0..31, pinned to XCD xd
  const int nt = yd >> 2;              // 0..7
  const int tm = mt * 128, tn = nt * 128;

  f32x4 acc[4][4] = {};
  gemm_bt_main<128, 128, 2, 2, true>(A, B, acc, tm, tn);

  const int tid = threadIdx.x, wave = tid >> 6, lane = tid & 63;
  const int wm = wave >> 1, wn = wave & 1;
  const int l16 = lane & 15, hi = lane >> 4;

  if (blockIdx.z < 2) {
    unsigned short* C = (blockIdx.z == 0) ? Qp : Kp;
    const float scale = (blockIdx.z == 0) ? 0.18033688011112042f : 1.0f; // 0.125*log2(e)
#pragma unroll
    for (int i = 0; i < 4; i++) {
      int row0 = tm + wm * 64 + i * 16 + hi * 4;
#pragma unroll
      for (int j = 0; j < 4; j++) {
        int col = tn + wn * 64 + j * 16 + l16;
        float bv2 = bias[col];
#pragma unroll
        for (int r = 0; r < 4; r++)
          C[(size_t)(row0 + r) * 1024 + col] = f2bf((acc[i][j][r] + bv2) * scale);
      }
    }
  } else {
    // transposed V write: lane's 4 rows are 4 consecutive s -> one 8B store
#pragma unroll
    for (int i = 0; i < 4; i++) {
      int row0 = tm + wm * 64 + i * 16 + hi * 4;
      int bb = row0 >> 11, s = row0 & 2047;
#pragma unroll
      for (int j = 0; j < 4; j++) {
        int col = tn + wn * 64 + j * 16 + l16;
        int hh = col >> 6, d = col & 63;
        float bv2 = bias[col];
        u32x2 w;
        w[0] = cvtpk(acc[i][j][0] + bv2, acc[i][j][1] + bv2);
        w[1] = cvtpk(acc[i][j][2] + bv2, acc[i][j][3] + bv2);
        *(u32x2*)&Vt[((size_t)(bb * 16 + hh) * 64 + d) * 2048 + s] = w;
      }
    }
  }
}

// Grid (16, 32). XCD = (x + 16y)%8 = x%8. Pin each Yb A-panel's 16 sharers to one XCD.
__global__ __launch_bounds__(256, 2) void out_gemm(
    const unsigned short* Yb, const unsigned short* wob, const float* bo, float* out)
{
  const int xd = blockIdx.x, yd = blockIdx.y;
  const int mt = (xd & 7) + 8 * (yd & 3);   // 0..31, pinned to XCD xd&7
  const int nt = (xd >> 3) + 2 * (yd >> 2); // 0..15
  const int tm = mt * 128, tn = nt * 64;

  f32x4 acc[2][4] = {};
  gemm_bt_main<128, 64, 4, 1, false>(Yb, wob, acc, tm, tn);

  const int tid = threadIdx.x, wave = tid >> 6, lane = tid & 63;
  const int l16 = lane & 15, hi = lane >> 4;
#pragma unroll
  for (int i = 0; i < 2; i++) {
    int row0 = tm + wave * 32 + i * 16 + hi * 4;
#pragma unroll
    for (int j = 0; j < 4; j++) {
      int col = tn + j * 16 + l16;
      float bv2 = bo[col];
#pragma unroll
      for (int r = 0; r < 4; r++)
        out[(size_t)(row0 + r) * 1024 + col] = acc[i][j][r] + bv2;
    }
  }
}

// ---------------------------------------------------------------- flash attention
// 4 waves x 32 q-rows = 128 q per block; grid (16,16,2). XCD = blockIdx.x%8.
// Remap so all 16 q-blocks of one (b,h) share an XCD -> K/V staging is L2-local.
// Swapped QK^T (log2 domain, scale folded into Q projection, -16 baked into MFMA
// C-init), constant-max softmax P = exp2(s'), permlane P repack, double-buffered
// K/V staging with counted vmcnt + pointer-marched sources, setprio on MFMA.
__global__ __launch_bounds__(256, 2) void attn_kernel(
    const unsigned short* __restrict__ Qp, const unsigned short* __restrict__ Kp,
    const unsigned short* __restrict__ Vt, const int* __restrict__ mask,
    unsigned short* __restrict__ Yb)
{
  constexpr int S = 2048, H = 1024;
  __shared__ __align__(16) unsigned short sK[2][128 * 64];  // K tiles (buf1 also Q staging)
  __shared__ __align__(16) unsigned short sV[2][64 * 128];  // V^T tiles [d][kv]

  const int tid = threadIdx.x, wave = tid >> 6, lane = tid & 63;
  const int l16 = lane & 15, hi = lane >> 4, swz = l16 & 7;
  const int xd = blockIdx.x, hd = blockIdx.y;
  const int h  = (xd & 7) + 8 * (hd & 1);            // pinned to XCD xd&7
  const int qt = ((xd >> 3) + 2 * (hd >> 1)) * 128;  // 0..15 q-tile
  const int b = blockIdx.z, bh = b * 16 + h;
  const unsigned short* Qb = Qp + (size_t)b * S * H + (size_t)h * 64;
  const unsigned short* Kb = Kp + (size_t)b * S * H + (size_t)h * 64;
  const unsigned short* Vb = Vt + (size_t)bh * 64 * 2048;

  // loop-invariant LDS read offsets (shorts)
  const int kinv0 = l16 * 64 + ((hi ^ swz) * 8);
  const int kinv1 = l16 * 64 + (((4 + hi) ^ swz) * 8);
  const int vinv0 = l16 * 128 + ((hi ^ swz) * 8);
  const int vinv1 = l16 * 128 + (((4 + hi) ^ swz) * 8);

  // ---- stage Q (128x64 = 16KB) into sK[1] while K0/V0 prefetch into buf 0
#pragma unroll
  for (int i = 0; i < 4; i++) {
    int p = i * 256 + tid, row = p >> 3, c = p & 7;
    load_lds16(Qb + (size_t)(qt + row) * H + ((c ^ (row & 7)) * 8),
               &sK[1][(i * 256 + wave * 64) * 8]);
  }
  // per-thread staging source pointers (advance by constants per tile)
  const unsigned short* pK[4]; const unsigned short* pV[4];
#pragma unroll
  for (int j = 0; j < 4; j++) {
    int g = j * 256 + tid;
    int row = g >> 3, c = g & 7;
    pK[j] = Kb + (size_t)row * H + ((c ^ (row & 7)) * 8);
    int d = g >> 4, kvc = g & 15;
    int sg = ((kvc ^ d) & 7) | (kvc & 8);
    pV[j] = Vb + (size_t)d * 2048 + sg * 8;
  }
#pragma unroll
  for (int j = 0; j < 4; j++)
    load_lds16(pK[j], &sK[0][(j * 256 + wave * 64) * 8]);
#pragma unroll
  for (int j = 0; j < 4; j++)
    load_lds16(pV[j], &sV[0][(j * 256 + wave * 64) * 8]);
#pragma unroll
  for (int j = 0; j < 4; j++) { pK[j] += 128 * H; pV[j] += 128; }

  asm volatile("s_waitcnt vmcnt(8)" ::: "memory");  // Q landed; K0/V0 still in flight
  __builtin_amdgcn_sched_barrier(0);
  __builtin_amdgcn_s_barrier();

  bf16x8 qf[2][2];
#pragma unroll
  for (int m = 0; m < 2; m++) {
    const int row = wave * 32 + m * 16 + l16;
    const int qm = mask[(size_t)b * S + qt + row];   // query-axis mask (matches ref)
#pragma unroll
    for (int ks = 0; ks < 2; ks++) {
      bf16x8 v = *(const bf16x8*)&sK[1][row * 64 + (((ks * 4 + hi) ^ swz) * 8)];
      u32x4 u = __builtin_bit_cast(u32x4, v);
#pragma unroll
      for (int c = 0; c < 4; c++) u[c] = qm ? u[c] : 0u;
      qf[m][ks] = __builtin_bit_cast(bf16x8, u);
    }
  }
  // all waves' Q-frag reads must land before t=0 stages into sK[1];
  // drain LDS reads only (K0/V0 global->LDS stay in flight on vmcnt)
  asm volatile("s_waitcnt lgkmcnt(0)" ::: "memory");
  __builtin_amdgcn_sched_barrier(0);
  __builtin_amdgcn_s_barrier();

  float lsum[2] = {0.f, 0.f};
  f32x4 oacc[2][4] = {};

  for (int t = 0; t < 16; t++) {
    const int cur = t & 1;
    // issue next-tile staging, then wait only for the CURRENT tile (counted vmcnt)
    if (t < 15) {
      unsigned short* nK = sK[cur ^ 1];
      unsigned short* nV = sV[cur ^ 1];
#pragma unroll
      for (int j = 0; j < 4; j++)
        load_lds16(pK[j], &nK[(j * 256 + wave * 64) * 8]);
#pragma unroll
      for (int j = 0; j < 4; j++)
        load_lds16(pV[j], &nV[(j * 256 + wave * 64) * 8]);
#pragma unroll
      for (int j = 0; j < 4; j++) { pK[j] += 128 * H; pV[j] += 128; }
      asm volatile("s_waitcnt vmcnt(8)" ::: "memory");
    } else {
      asm volatile("s_waitcnt vmcnt(0)" ::: "memory");
    }
    __builtin_amdgcn_sched_barrier(0);
    __builtin_amdgcn_s_barrier();

    const unsigned short* kb = sK[cur];
    const unsigned short* vb = sV[cur];

    // process the 128-kv tile in two 64-kv halves (bounds sf register pressure)
#pragma unroll
    for (int hf = 0; hf < 2; hf++) {
      // ---- QK^T swapped: sf[m][jj] = S - 16 (log2 domain, shift baked into C-init)
      f32x4 sf[2][4];
      __builtin_amdgcn_s_setprio(1);
#pragma unroll
      for (int jj = 0; jj < 4; jj++) {
        const int ro = (hf * 4 + jj) * 1024;
        bf16x8 kf0 = *(const bf16x8*)&kb[ro + kinv0];
        bf16x8 kf1 = *(const bf16x8*)&kb[ro + kinv1];
#pragma unroll
        for (int m = 0; m < 2; m++) {
          f32x4 acc = {-16.0f, -16.0f, -16.0f, -16.0f};
          acc = __builtin_amdgcn_mfma_f32_16x16x32_bf16(kf0, qf[m][0], acc, 0, 0, 0);
          acc = __builtin_amdgcn_mfma_f32_16x16x32_bf16(kf1, qf[m][1], acc, 0, 0, 0);
          sf[m][jj] = acc;
        }
      }
      __builtin_amdgcn_s_setprio(0);

      // ---- constant-max softmax: P = exp2(s') (shift already applied)
#pragma unroll
      for (int m = 0; m < 2; m++) {
#pragma unroll
        for (int jj = 0; jj < 4; jj++)
#pragma unroll
          for (int r = 0; r < 4; r++)
            sf[m][jj][r] = fexp2(sf[m][jj][r]);
        f32x4 c4 = (sf[m][0] + sf[m][1]) + (sf[m][2] + sf[m][3]);
        lsum[m] += (c4[0] + c4[1]) + (c4[2] + c4[3]);
      }

      // ---- P repack (permlane) + PV per 32-kv window; V-frag shared across m
#pragma unroll
      for (int w2 = 0; w2 < 2; w2++) {
        bf16x8 af0 = repack_af(sf[0][2 * w2], sf[0][2 * w2 + 1]);
        bf16x8 af1 = repack_af(sf[1][2 * w2], sf[1][2 * w2 + 1]);
        const int gw = hf * 2 + w2;
        const int vo = ((gw & 2) ? 64 : 0) + ((gw & 1) ? vinv1 : vinv0);
        __builtin_amdgcn_s_setprio(1);
#pragma unroll
        for (int n = 0; n < 4; n++) {
          bf16x8 vf = *(const bf16x8*)&vb[n * 2048 + vo];
          oacc[0][n] = __builtin_amdgcn_mfma_f32_16x16x32_bf16(af0, vf, oacc[0][n], 0, 0, 0);
          oacc[1][n] = __builtin_amdgcn_mfma_f32_16x16x32_bf16(af1, vf, oacc[1][n], 0, 0, 0);
        }
        __builtin_amdgcn_s_setprio(0);
      }
    }
    __builtin_amdgcn_sched_barrier(0);
    __builtin_amdgcn_s_barrier();
  }

  // ---- epilogue: reduce denominators once, then O / l -> Yb (bf16)
#pragma unroll
  for (int m = 0; m < 2; m++) {
    lsum[m] += __shfl_xor(lsum[m], 16);
    lsum[m] += __shfl_xor(lsum[m], 32);
  }
#pragma unroll
  for (int m = 0; m < 2; m++) {
    float lr[4];
#pragma unroll
    for (int r = 0; r < 4; r++) lr[r] = 1.0f / __shfl(lsum[m], hi * 4 + r);
#pragma unroll
    for (int n = 0; n < 4; n++)
#pragma unroll
      for (int r = 0; r < 4; r++) {
        int row = qt + wave * 32 + m * 16 + hi * 4 + r;
        int col = n * 16 + l16;
        Yb[((size_t)b * S + row) * H + h * 64 + col] = f2bf(oacc[m][n][r] * lr[r]);
      }
  }
}

// ---------------------------------------------------------------- launch
extern "C" void kernel_launch(void* const* d_in, const int* in_sizes, int n_in,
                              void* d_out, int out_size, void* d_ws, size_t ws_size,
                              hipStream_t stream)
{
  const float* q  = (const float*)d_in[0];
  const float* k  = (const float*)d_in[1];
  const float* v  = (const float*)d_in[2];
  const int*  mask = (const int*)d_in[3];
  const float* Wq = (const float*)d_in[4];
  const float* bq = (const float*)d_in[5];
  const float* Wk = (const float*)d_in[6];
  const float* bk = (const float*)d_in[7];
  const float* Wv = (const float*)d_in[8];
  const float* bv = (const float*)d_in[9];
  const float* Wo = (const float*)d_in[10];
  const float* bo = (const float*)d_in[11];

  unsigned short* ws  = (unsigned short*)d_ws;
  unsigned short* wqb = ws;                 //  0..1 EL (bf16 weights)
  unsigned short* wkb = ws + 1 * EL;        //  1..2
  unsigned short* wvb = ws + 2 * EL;        //  2..3
  unsigned short* wob = ws + 3 * EL;        //  3..4
  unsigned short* Qp  = ws + 4 * EL;        //  4..8
  unsigned short* Kp  = ws + 8 * EL;        //  8..12
  unsigned short* Vt  = ws + 12 * EL;       // 12..16  [32][64][2048] bf16
  unsigned short* Yb  = ws + 16 * EL;       // 16..20

  convert_w<<<1024, 256, 0, stream>>>(Wq, Wk, Wv, Wo, ws);
  qkv_gemm<<<dim3(8, 32, 3), 256, 0, stream>>>(q, k, v, wqb, wkb, wvb,
                                               bq, bk, bv, Qp, Kp, Vt);
  attn_kernel<<<dim3(16, 16, 2), 256, 0, stream>>>(Qp, Kp, Vt, mask, Yb);
  out_gemm<<<dim3(16, 32), 256, 0, stream>>>(Yb, wob, bo, (float*)d_out);
}

// Round 13
// 108.261 us; speedup vs baseline: 1.3123x; 1.0128x over previous
//
#include <hip/hip_runtime.h>
#include <hip/hip_bf16.h>
#include <cstdint>

#define EL 1048576ull   // 1Mi elements

typedef __bf16 bf16_t;
typedef bf16_t bf16x8 __attribute__((ext_vector_type(8)));
typedef float  f32x4  __attribute__((ext_vector_type(4)));
typedef unsigned int u32x2 __attribute__((ext_vector_type(2)));
typedef unsigned int u32x4 __attribute__((ext_vector_type(4)));

__device__ __forceinline__ unsigned short f2bf(float f) {
  unsigned int u = __builtin_bit_cast(unsigned int, f);
  u += 0x7FFFu + ((u >> 16) & 1u);   // RNE
  return (unsigned short)(u >> 16);
}

// pack 2 f32 -> 2 bf16 in one u32 (lo -> low half), RNE; proven round 5
__device__ __forceinline__ unsigned int cvtpk(float lo, float hi2) {
  unsigned int r;
  asm("v_cvt_pk_bf16_f32 %0, %1, %2" : "=v"(r) : "v"(lo), "v"(hi2));
  return r;
}

__device__ __forceinline__ float fexp2(float x) {
#if __has_builtin(__builtin_amdgcn_exp2f)
  return __builtin_amdgcn_exp2f(x);
#else
  return exp2f(x);
#endif
}

typedef __attribute__((address_space(1))) void as1_void;
typedef __attribute__((address_space(3))) void as3_void;
__device__ __forceinline__ void load_lds16(const void* g, void* l) {
  __builtin_amdgcn_global_load_lds((as1_void*)g, (as3_void*)l, 16, 0, 0);
}

// P repack via permlane swaps (VALU, no LDS pipe); proven round 6
__device__ __forceinline__ bf16x8 repack_af(const f32x4 s0v, const f32x4 s1v) {
  unsigned int c00 = cvtpk(s0v[0], s0v[1]);
  unsigned int c01 = cvtpk(s0v[2], s0v[3]);
  unsigned int c10 = cvtpk(s1v[0], s1v[1]);
  unsigned int c11 = cvtpk(s1v[2], s1v[3]);
  asm("v_permlane32_swap_b32 %0, %1" : "+v"(c00), "+v"(c10));
  asm("v_permlane16_swap_b32 %0, %1" : "+v"(c00), "+v"(c10));
  asm("v_permlane32_swap_b32 %0, %1" : "+v"(c01), "+v"(c11));
  asm("v_permlane16_swap_b32 %0, %1" : "+v"(c01), "+v"(c11));
  u32x4 wd; wd[0] = c00; wd[1] = c01; wd[2] = c10; wd[3] = c11;
  return __builtin_bit_cast(bf16x8, wd);
}

// ---------------------------------------------------------------- convert
__global__ __launch_bounds__(256) void convert_all(
    const float* __restrict__ q, const float* __restrict__ k, const float* __restrict__ v,
    const float* __restrict__ wq, const float* __restrict__ wk,
    const float* __restrict__ wv, const float* __restrict__ wo,
    unsigned short* __restrict__ ws)
{
  const size_t total_v4 = 4 * EL; // 16M elems / 4
  for (size_t v4 = (size_t)blockIdx.x * blockDim.x + threadIdx.x; v4 < total_v4;
       v4 += (size_t)gridDim.x * blockDim.x) {
    size_t e = v4 * 4;
    unsigned seg = (unsigned)(e >> 20);
    const float* s; size_t base;
    if      (seg < 4)   { s = q;  base = 0; }
    else if (seg < 8)   { s = k;  base = 4*EL; }
    else if (seg < 12)  { s = v;  base = 8*EL; }
    else if (seg == 12) { s = wq; base = 12*EL; }
    else if (seg == 13) { s = wk; base = 13*EL; }
    else if (seg == 14) { s = wv; base = 14*EL; }
    else                { s = wo; base = 15*EL; }
    const float4 f = *(const float4*)(s + (e - base));
    ushort4 o;
    o.x = f2bf(f.x); o.y = f2bf(f.y); o.z = f2bf(f.z); o.w = f2bf(f.w);
    *(ushort4*)(ws + e) = o;
  }
}

// ---------------------------------------------------------------- GEMM main loop (acc += A * B^T)
// A: [M][1024] bf16, B: [1024][1024] bf16 (row n holds B[n][k]).
// XOR-swizzled LDS, global_load_lds staging (pre-swizzled global source).
template <int BM, int BN, int WM, int WN>
__device__ __forceinline__ void gemm_bt_main(
    const unsigned short* __restrict__ A,
    const unsigned short* __restrict__ B,
    f32x4 (&acc)[BM / WM / 16][BN / WN / 16],
    const int tm, const int tn)
{
  constexpr int K = 1024, BK = 64;
  constexpr int AM = BM / WM / 16, AN = BN / WN / 16;
  __shared__ __align__(16) unsigned short sA[BM * BK];
  __shared__ __align__(16) unsigned short sB[BN * BK];
  const int tid  = threadIdx.x;
  const int wave = tid >> 6, lane = tid & 63;
  const int wm = wave / WN, wn = wave % WN;
  const int l16 = lane & 15, hi = lane >> 4, swz = l16 & 7;

  for (int k0 = 0; k0 < K; k0 += BK) {
    __syncthreads();
#pragma unroll
    for (int i = 0; i < BM * 8 / 256; i++) {
      int p = i * 256 + tid;
      int row = p >> 3, c = p & 7;
      load_lds16(A + (size_t)(tm + row) * K + k0 + ((c ^ (row & 7)) * 8),
                 &sA[(i * 256 + wave * 64) * 8]);
    }
#pragma unroll
    for (int i = 0; i < BN * 8 / 256; i++) {
      int p = i * 256 + tid;
      int row = p >> 3, c = p & 7;
      load_lds16(B + (size_t)(tn + row) * K + k0 + ((c ^ (row & 7)) * 8),
                 &sB[(i * 256 + wave * 64) * 8]);
    }
    __syncthreads();

#pragma unroll
    for (int kk = 0; kk < 2; kk++) {
      bf16x8 af[AM], bfr[AN];
#pragma unroll
      for (int i = 0; i < AM; i++) {
        int row = wm * (BM / WM) + i * 16 + l16;
        af[i] = *(const bf16x8*)&sA[row * BK + (((kk * 4 + hi) ^ swz) * 8)];
      }
#pragma unroll
      for (int j = 0; j < AN; j++) {
        int row = wn * (BN / WN) + j * 16 + l16;
        bfr[j] = *(const bf16x8*)&sB[row * BK + (((kk * 4 + hi) ^ swz) * 8)];
      }
#pragma unroll
      for (int i = 0; i < AM; i++)
#pragma unroll
        for (int j = 0; j < AN; j++)
          acc[i][j] = __builtin_amdgcn_mfma_f32_16x16x32_bf16(af[i], bfr[j], acc[i][j], 0, 0, 0);
    }
  }
}

// ---------------------------------------------------------------- QKV projections
// Grid (8, 32, 3). XCD = dispatch_linear % 8 = blockIdx.x. Remap so the 8 N-tiles
// sharing an A-panel all carry the same blockIdx.x -> same XCD -> A panel is
// fetched from HBM once and re-read from that XCD's L2.
__global__ __launch_bounds__(256, 3) void qkv_gemm(
    const unsigned short* qb, const unsigned short* kb, const unsigned short* vb,
    const unsigned short* wqb, const unsigned short* wkb, const unsigned short* wvb,
    const float* bq, const float* bk, const float* bv,
    unsigned short* Qp, unsigned short* Kp, unsigned short* Vt)
{
  const unsigned short* A; const unsigned short* B; const float* bias;
  if (blockIdx.z == 0)      { A = qb; B = wqb; bias = bq; }
  else if (blockIdx.z == 1) { A = kb; B = wkb; bias = bk; }
  else                      { A = vb; B = wvb; bias = bv; }

  const int xd = blockIdx.x, yd = blockIdx.y;
  const int mt = xd + 8 * (yd & 3);    // A-panel id 0..31, pinned to XCD xd
  const int nt = yd >> 2;              // 0..7
  const int tm = mt * 128, tn = nt * 128;

  f32x4 acc[4][4] = {};
  gemm_bt_main<128, 128, 2, 2>(A, B, acc, tm, tn);

  const int tid = threadIdx.x, wave = tid >> 6, lane = tid & 63;
  const int wm = wave >> 1, wn = wave & 1;
  const int l16 = lane & 15, hi = lane >> 4;

  if (blockIdx.z < 2) {
    unsigned short* C = (blockIdx.z == 0) ? Qp : Kp;
    const float scale = (blockIdx.z == 0) ? 0.18033688011112042f : 1.0f; // 0.125*log2(e)
#pragma unroll
    for (int i = 0; i < 4; i++) {
      int row0 = tm + wm * 64 + i * 16 + hi * 4;
#pragma unroll
      for (int j = 0; j < 4; j++) {
        int col = tn + wn * 64 + j * 16 + l16;
        float bv2 = bias[col];
#pragma unroll
        for (int r = 0; r < 4; r++)
          C[(size_t)(row0 + r) * 1024 + col] = f2bf((acc[i][j][r] + bv2) * scale);
      }
    }
  } else {
    // transposed V write: lane's 4 rows are 4 consecutive s -> one 8B store
#pragma unroll
    for (int i = 0; i < 4; i++) {
      int row0 = tm + wm * 64 + i * 16 + hi * 4;
      int bb = row0 >> 11, s = row0 & 2047;
#pragma unroll
      for (int j = 0; j < 4; j++) {
        int col = tn + wn * 64 + j * 16 + l16;
        int hh = col >> 6, d = col & 63;
        float bv2 = bias[col];
        u32x2 w;
        w[0] = cvtpk(acc[i][j][0] + bv2, acc[i][j][1] + bv2);
        w[1] = cvtpk(acc[i][j][2] + bv2, acc[i][j][3] + bv2);
        *(u32x2*)&Vt[((size_t)(bb * 16 + hh) * 64 + d) * 2048 + s] = w;
      }
    }
  }
}

// Grid (16, 32). XCD = (x + 16y)%8 = x%8. Pin each Yb A-panel's 16 sharers to one XCD.
__global__ __launch_bounds__(256, 2) void out_gemm(
    const unsigned short* Yb, const unsigned short* wob, const float* bo, float* out)
{
  const int xd = blockIdx.x, yd = blockIdx.y;
  const int mt = (xd & 7) + 8 * (yd & 3);   // 0..31, pinned to XCD xd&7
  const int nt = (xd >> 3) + 2 * (yd >> 2); // 0..15
  const int tm = mt * 128, tn = nt * 64;

  f32x4 acc[2][4] = {};
  gemm_bt_main<128, 64, 4, 1>(Yb, wob, acc, tm, tn);

  const int tid = threadIdx.x, wave = tid >> 6, lane = tid & 63;
  const int l16 = lane & 15, hi = lane >> 4;
#pragma unroll
  for (int i = 0; i < 2; i++) {
    int row0 = tm + wave * 32 + i * 16 + hi * 4;
#pragma unroll
    for (int j = 0; j < 4; j++) {
      int col = tn + j * 16 + l16;
      float bv2 = bo[col];
#pragma unroll
      for (int r = 0; r < 4; r++)
        out[(size_t)(row0 + r) * 1024 + col] = acc[i][j][r] + bv2;
    }
  }
}

// ---------------------------------------------------------------- flash attention
// 4 waves x 32 q-rows = 128 q per block; grid (16,16,2). XCD = blockIdx.x%8.
// Remap so all 16 q-blocks of one (b,h) share an XCD -> K/V staging is L2-local.
// Swapped QK^T (log2 domain, scale folded into Q projection, -16 baked into MFMA
// C-init), constant-max softmax P = exp2(s'), permlane P repack, double-buffered
// K/V staging with counted vmcnt + pointer-marched sources, setprio on MFMA.
__global__ __launch_bounds__(256, 2) void attn_kernel(
    const unsigned short* __restrict__ Qp, const unsigned short* __restrict__ Kp,
    const unsigned short* __restrict__ Vt, const int* __restrict__ mask,
    unsigned short* __restrict__ Yb)
{
  constexpr int S = 2048, H = 1024;
  __shared__ __align__(16) unsigned short sK[2][128 * 64];  // K tiles (buf1 also Q staging)
  __shared__ __align__(16) unsigned short sV[2][64 * 128];  // V^T tiles [d][kv]

  const int tid = threadIdx.x, wave = tid >> 6, lane = tid & 63;
  const int l16 = lane & 15, hi = lane >> 4, swz = l16 & 7;
  const int xd = blockIdx.x, hd = blockIdx.y;
  const int h  = (xd & 7) + 8 * (hd & 1);            // pinned to XCD xd&7
  const int qt = ((xd >> 3) + 2 * (hd >> 1)) * 128;  // 0..15 q-tile
  const int b = blockIdx.z, bh = b * 16 + h;
  const unsigned short* Qb = Qp + (size_t)b * S * H + (size_t)h * 64;
  const unsigned short* Kb = Kp + (size_t)b * S * H + (size_t)h * 64;
  const unsigned short* Vb = Vt + (size_t)bh * 64 * 2048;

  // loop-invariant LDS read offsets (shorts)
  const int kinv0 = l16 * 64 + ((hi ^ swz) * 8);
  const int kinv1 = l16 * 64 + (((4 + hi) ^ swz) * 8);
  const int vinv0 = l16 * 128 + ((hi ^ swz) * 8);
  const int vinv1 = l16 * 128 + (((4 + hi) ^ swz) * 8);

  // ---- stage Q (128x64 = 16KB) into sK[1] while K0/V0 prefetch into buf 0
#pragma unroll
  for (int i = 0; i < 4; i++) {
    int p = i * 256 + tid, row = p >> 3, c = p & 7;
    load_lds16(Qb + (size_t)(qt + row) * H + ((c ^ (row & 7)) * 8),
               &sK[1][(i * 256 + wave * 64) * 8]);
  }
  // per-thread staging source pointers (advance by constants per tile)
  const unsigned short* pK[4]; const unsigned short* pV[4];
#pragma unroll
  for (int j = 0; j < 4; j++) {
    int g = j * 256 + tid;
    int row = g >> 3, c = g & 7;
    pK[j] = Kb + (size_t)row * H + ((c ^ (row & 7)) * 8);
    int d = g >> 4, kvc = g & 15;
    int sg = ((kvc ^ d) & 7) | (kvc & 8);
    pV[j] = Vb + (size_t)d * 2048 + sg * 8;
  }
#pragma unroll
  for (int j = 0; j < 4; j++)
    load_lds16(pK[j], &sK[0][(j * 256 + wave * 64) * 8]);
#pragma unroll
  for (int j = 0; j < 4; j++)
    load_lds16(pV[j], &sV[0][(j * 256 + wave * 64) * 8]);
#pragma unroll
  for (int j = 0; j < 4; j++) { pK[j] += 128 * H; pV[j] += 128; }

  asm volatile("s_waitcnt vmcnt(8)" ::: "memory");  // Q landed; K0/V0 still in flight
  __builtin_amdgcn_sched_barrier(0);
  __builtin_amdgcn_s_barrier();

  bf16x8 qf[2][2];
#pragma unroll
  for (int m = 0; m < 2; m++) {
    const int row = wave * 32 + m * 16 + l16;
    const int qm = mask[(size_t)b * S + qt + row];   // query-axis mask (matches ref)
#pragma unroll
    for (int ks = 0; ks < 2; ks++) {
      bf16x8 v = *(const bf16x8*)&sK[1][row * 64 + (((ks * 4 + hi) ^ swz) * 8)];
      u32x4 u = __builtin_bit_cast(u32x4, v);
#pragma unroll
      for (int c = 0; c < 4; c++) u[c] = qm ? u[c] : 0u;
      qf[m][ks] = __builtin_bit_cast(bf16x8, u);
    }
  }
  // all waves' Q-frag reads must land before t=0 stages into sK[1];
  // drain LDS reads only (K0/V0 global->LDS stay in flight on vmcnt)
  asm volatile("s_waitcnt lgkmcnt(0)" ::: "memory");
  __builtin_amdgcn_sched_barrier(0);
  __builtin_amdgcn_s_barrier();

  float lsum[2] = {0.f, 0.f};
  f32x4 oacc[2][4] = {};

  for (int t = 0; t < 16; t++) {
    const int cur = t & 1;
    // issue next-tile staging, then wait only for the CURRENT tile (counted vmcnt)
    if (t < 15) {
      unsigned short* nK = sK[cur ^ 1];
      unsigned short* nV = sV[cur ^ 1];
#pragma unroll
      for (int j = 0; j < 4; j++)
        load_lds16(pK[j], &nK[(j * 256 + wave * 64) * 8]);
#pragma unroll
      for (int j = 0; j < 4; j++)
        load_lds16(pV[j], &nV[(j * 256 + wave * 64) * 8]);
#pragma unroll
      for (int j = 0; j < 4; j++) { pK[j] += 128 * H; pV[j] += 128; }
      asm volatile("s_waitcnt vmcnt(8)" ::: "memory");
    } else {
      asm volatile("s_waitcnt vmcnt(0)" ::: "memory");
    }
    __builtin_amdgcn_sched_barrier(0);
    __builtin_amdgcn_s_barrier();

    const unsigned short* kb = sK[cur];
    const unsigned short* vb = sV[cur];

    // process the 128-kv tile in two 64-kv halves (bounds sf register pressure)
#pragma unroll
    for (int hf = 0; hf < 2; hf++) {
      // ---- QK^T swapped: sf[m][jj] = S - 16 (log2 domain, shift baked into C-init)
      f32x4 sf[2][4];
      __builtin_amdgcn_s_setprio(1);
#pragma unroll
      for (int jj = 0; jj < 4; jj++) {
        const int ro = (hf * 4 + jj) * 1024;
        bf16x8 kf0 = *(const bf16x8*)&kb[ro + kinv0];
        bf16x8 kf1 = *(const bf16x8*)&kb[ro + kinv1];
#pragma unroll
        for (int m = 0; m < 2; m++) {
          f32x4 acc = {-16.0f, -16.0f, -16.0f, -16.0f};
          acc = __builtin_amdgcn_mfma_f32_16x16x32_bf16(kf0, qf[m][0], acc, 0, 0, 0);
          acc = __builtin_amdgcn_mfma_f32_16x16x32_bf16(kf1, qf[m][1], acc, 0, 0, 0);
          sf[m][jj] = acc;
        }
      }
      __builtin_amdgcn_s_setprio(0);

      // ---- constant-max softmax: P = exp2(s') (shift already applied)
#pragma unroll
      for (int m = 0; m < 2; m++) {
#pragma unroll
        for (int jj = 0; jj < 4; jj++)
#pragma unroll
          for (int r = 0; r < 4; r++)
            sf[m][jj][r] = fexp2(sf[m][jj][r]);
        f32x4 c4 = (sf[m][0] + sf[m][1]) + (sf[m][2] + sf[m][3]);
        lsum[m] += (c4[0] + c4[1]) + (c4[2] + c4[3]);
      }

      // ---- P repack (permlane) + PV per 32-kv window; V-frag shared across m
#pragma unroll
      for (int w2 = 0; w2 < 2; w2++) {
        bf16x8 af0 = repack_af(sf[0][2 * w2], sf[0][2 * w2 + 1]);
        bf16x8 af1 = repack_af(sf[1][2 * w2], sf[1][2 * w2 + 1]);
        const int gw = hf * 2 + w2;
        const int vo = ((gw & 2) ? 64 : 0) + ((gw & 1) ? vinv1 : vinv0);
        __builtin_amdgcn_s_setprio(1);
#pragma unroll
        for (int n = 0; n < 4; n++) {
          bf16x8 vf = *(const bf16x8*)&vb[n * 2048 + vo];
          oacc[0][n] = __builtin_amdgcn_mfma_f32_16x16x32_bf16(af0, vf, oacc[0][n], 0, 0, 0);
          oacc[1][n] = __builtin_amdgcn_mfma_f32_16x16x32_bf16(af1, vf, oacc[1][n], 0, 0, 0);
        }
        __builtin_amdgcn_s_setprio(0);
      }
    }
    __builtin_amdgcn_sched_barrier(0);
    __builtin_amdgcn_s_barrier();
  }

  // ---- epilogue: reduce denominators once, then O / l -> Yb (bf16)
#pragma unroll
  for (int m = 0; m < 2; m++) {
    lsum[m] += __shfl_xor(lsum[m], 16);
    lsum[m] += __shfl_xor(lsum[m], 32);
  }
#pragma unroll
  for (int m = 0; m < 2; m++) {
    float lr[4];
#pragma unroll
    for (int r = 0; r < 4; r++) lr[r] = 1.0f / __shfl(lsum[m], hi * 4 + r);
#pragma unroll
    for (int n = 0; n < 4; n++)
#pragma unroll
      for (int r = 0; r < 4; r++) {
        int row = qt + wave * 32 + m * 16 + hi * 4 + r;
        int col = n * 16 + l16;
        Yb[((size_t)b * S + row) * H + h * 64 + col] = f2bf(oacc[m][n][r] * lr[r]);
      }
  }
}

// ---------------------------------------------------------------- launch
extern "C" void kernel_launch(void* const* d_in, const int* in_sizes, int n_in,
                              void* d_out, int out_size, void* d_ws, size_t ws_size,
                              hipStream_t stream)
{
  const float* q  = (const float*)d_in[0];
  const float* k  = (const float*)d_in[1];
  const float* v  = (const float*)d_in[2];
  const int*  mask = (const int*)d_in[3];
  const float* Wq = (const float*)d_in[4];
  const float* bq = (const float*)d_in[5];
  const float* Wk = (const float*)d_in[6];
  const float* bk = (const float*)d_in[7];
  const float* Wv = (const float*)d_in[8];
  const float* bv = (const float*)d_in[9];
  const float* Wo = (const float*)d_in[10];
  const float* bo = (const float*)d_in[11];

  unsigned short* ws  = (unsigned short*)d_ws;
  unsigned short* qb  = ws;                 //  0..4  EL
  unsigned short* kb  = ws + 4 * EL;        //  4..8
  unsigned short* vb  = ws + 8 * EL;        //  8..12
  unsigned short* wqb = ws + 12 * EL;       // 12..13
  unsigned short* wkb = ws + 13 * EL;       // 13..14
  unsigned short* wvb = ws + 14 * EL;       // 14..15
  unsigned short* wob = ws + 15 * EL;       // 15..16
  unsigned short* Qp  = ws + 16 * EL;       // 16..20
  unsigned short* Kp  = ws + 20 * EL;       // 20..24
  unsigned short* Vt  = ws + 24 * EL;       // 24..28  [32][64][2048] bf16
  unsigned short* Yb  = ws + 28 * EL;       // 28..32

  convert_all<<<2048, 256, 0, stream>>>(q, k, v, Wq, Wk, Wv, Wo, ws);
  qkv_gemm<<<dim3(8, 32, 3), 256, 0, stream>>>(qb, kb, vb, wqb, wkb, wvb,
                                               bq, bk, bv, Qp, Kp, Vt);
  attn_kernel<<<dim3(16, 16, 2), 256, 0, stream>>>(Qp, Kp, Vt, mask, Yb);
  out_gemm<<<dim3(16, 32), 256, 0, stream>>>(Yb, wob, bo, (float*)d_out);
}

// Round 15
// 104.782 us; speedup vs baseline: 1.3559x; 1.0332x over previous
//
#include <hip/hip_runtime.h>
#include <hip/hip_bf16.h>
#include <cstdint>

#define EL 1048576ull   // 1Mi elements

typedef __bf16 bf16_t;
typedef bf16_t bf16x8 __attribute__((ext_vector_type(8)));
typedef float  f32x4  __attribute__((ext_vector_type(4)));
typedef unsigned int u32x2 __attribute__((ext_vector_type(2)));
typedef unsigned int u32x4 __attribute__((ext_vector_type(4)));

__device__ __forceinline__ unsigned short f2bf(float f) {
  unsigned int u = __builtin_bit_cast(unsigned int, f);
  u += 0x7FFFu + ((u >> 16) & 1u);   // RNE
  return (unsigned short)(u >> 16);
}

// pack 2 f32 -> 2 bf16 in one u32 (lo -> low half), RNE; proven round 5
__device__ __forceinline__ unsigned int cvtpk(float lo, float hi2) {
  unsigned int r;
  asm("v_cvt_pk_bf16_f32 %0, %1, %2" : "=v"(r) : "v"(lo), "v"(hi2));
  return r;
}

__device__ __forceinline__ float fexp2(float x) {
#if __has_builtin(__builtin_amdgcn_exp2f)
  return __builtin_amdgcn_exp2f(x);
#else
  return exp2f(x);
#endif
}

typedef __attribute__((address_space(1))) void as1_void;
typedef __attribute__((address_space(3))) void as3_void;
__device__ __forceinline__ void load_lds16(const void* g, void* l) {
  __builtin_amdgcn_global_load_lds((as1_void*)g, (as3_void*)l, 16, 0, 0);
}

// P repack via permlane swaps (VALU, no LDS pipe); proven round 6
__device__ __forceinline__ bf16x8 repack_af(const f32x4 s0v, const f32x4 s1v) {
  unsigned int c00 = cvtpk(s0v[0], s0v[1]);
  unsigned int c01 = cvtpk(s0v[2], s0v[3]);
  unsigned int c10 = cvtpk(s1v[0], s1v[1]);
  unsigned int c11 = cvtpk(s1v[2], s1v[3]);
  asm("v_permlane32_swap_b32 %0, %1" : "+v"(c00), "+v"(c10));
  asm("v_permlane16_swap_b32 %0, %1" : "+v"(c00), "+v"(c10));
  asm("v_permlane32_swap_b32 %0, %1" : "+v"(c01), "+v"(c11));
  asm("v_permlane16_swap_b32 %0, %1" : "+v"(c01), "+v"(c11));
  u32x4 wd; wd[0] = c00; wd[1] = c01; wd[2] = c10; wd[3] = c11;
  return __builtin_bit_cast(bf16x8, wd);
}

// ---------------------------------------------------------------- convert
__global__ __launch_bounds__(256) void convert_all(
    const float* __restrict__ q, const float* __restrict__ k, const float* __restrict__ v,
    const float* __restrict__ wq, const float* __restrict__ wk,
    const float* __restrict__ wv, const float* __restrict__ wo,
    unsigned short* __restrict__ ws)
{
  const size_t total_v4 = 4 * EL; // 16M elems / 4
  for (size_t v4 = (size_t)blockIdx.x * blockDim.x + threadIdx.x; v4 < total_v4;
       v4 += (size_t)gridDim.x * blockDim.x) {
    size_t e = v4 * 4;
    unsigned seg = (unsigned)(e >> 20);
    const float* s; size_t base;
    if      (seg < 4)   { s = q;  base = 0; }
    else if (seg < 8)   { s = k;  base = 4*EL; }
    else if (seg < 12)  { s = v;  base = 8*EL; }
    else if (seg == 12) { s = wq; base = 12*EL; }
    else if (seg == 13) { s = wk; base = 13*EL; }
    else if (seg == 14) { s = wv; base = 14*EL; }
    else                { s = wo; base = 15*EL; }
    const float4 f = *(const float4*)(s + (e - base));
    ushort4 o;
    o.x = f2bf(f.x); o.y = f2bf(f.y); o.z = f2bf(f.z); o.w = f2bf(f.w);
    *(ushort4*)(ws + e) = o;
  }
}

// ---------------------------------------------------------------- GEMM main loop (acc += A * B^T)
template <int BM, int BN, int WM, int WN>
__device__ __forceinline__ void gemm_bt_main(
    const unsigned short* __restrict__ A,
    const unsigned short* __restrict__ B,
    f32x4 (&acc)[BM / WM / 16][BN / WN / 16],
    const int tm, const int tn)
{
  constexpr int K = 1024, BK = 64;
  constexpr int AM = BM / WM / 16, AN = BN / WN / 16;
  __shared__ __align__(16) unsigned short sA[BM * BK];
  __shared__ __align__(16) unsigned short sB[BN * BK];
  const int tid  = threadIdx.x;
  const int wave = tid >> 6, lane = tid & 63;
  const int wm = wave / WN, wn = wave % WN;
  const int l16 = lane & 15, hi = lane >> 4, swz = l16 & 7;

  for (int k0 = 0; k0 < K; k0 += BK) {
    __syncthreads();
#pragma unroll
    for (int i = 0; i < BM * 8 / 256; i++) {
      int p = i * 256 + tid;
      int row = p >> 3, c = p & 7;
      load_lds16(A + (size_t)(tm + row) * K + k0 + ((c ^ (row & 7)) * 8),
                 &sA[(i * 256 + wave * 64) * 8]);
    }
#pragma unroll
    for (int i = 0; i < BN * 8 / 256; i++) {
      int p = i * 256 + tid;
      int row = p >> 3, c = p & 7;
      load_lds16(B + (size_t)(tn + row) * K + k0 + ((c ^ (row & 7)) * 8),
                 &sB[(i * 256 + wave * 64) * 8]);
    }
    __syncthreads();

#pragma unroll
    for (int kk = 0; kk < 2; kk++) {
      bf16x8 af[AM], bfr[AN];
#pragma unroll
      for (int i = 0; i < AM; i++) {
        int row = wm * (BM / WM) + i * 16 + l16;
        af[i] = *(const bf16x8*)&sA[row * BK + (((kk * 4 + hi) ^ swz) * 8)];
      }
#pragma unroll
      for (int j = 0; j < AN; j++) {
        int row = wn * (BN / WN) + j * 16 + l16;
        bfr[j] = *(const bf16x8*)&sB[row * BK + (((kk * 4 + hi) ^ swz) * 8)];
      }
#pragma unroll
      for (int i = 0; i < AM; i++)
#pragma unroll
        for (int j = 0; j < AN; j++)
          acc[i][j] = __builtin_amdgcn_mfma_f32_16x16x32_bf16(af[i], bfr[j], acc[i][j], 0, 0, 0);
    }
  }
}

// ---------------------------------------------------------------- QKV projections
// Grid (8, 32, 3). XCD = blockIdx.x. A-panel's 8 sharers pinned to one XCD.
__global__ __launch_bounds__(256, 3) void qkv_gemm(
    const unsigned short* qb, const unsigned short* kb, const unsigned short* vb,
    const unsigned short* wqb, const unsigned short* wkb, const unsigned short* wvb,
    const float* bq, const float* bk, const float* bv,
    unsigned short* Qp, unsigned short* Kp, unsigned short* Vt)
{
  const unsigned short* A; const unsigned short* B; const float* bias;
  if (blockIdx.z == 0)      { A = qb; B = wqb; bias = bq; }
  else if (blockIdx.z == 1) { A = kb; B = wkb; bias = bk; }
  else                      { A = vb; B = wvb; bias = bv; }

  const int xd = blockIdx.x, yd = blockIdx.y;
  const int mt = xd + 8 * (yd & 3);    // A-panel id 0..31, pinned to XCD xd
  const int nt = yd >> 2;              // 0..7
  const int tm = mt * 128, tn = nt * 128;

  f32x4 acc[4][4] = {};
  gemm_bt_main<128, 128, 2, 2>(A, B, acc, tm, tn);

  const int tid = threadIdx.x, wave = tid >> 6, lane = tid & 63;
  const int wm = wave >> 1, wn = wave & 1;
  const int l16 = lane & 15, hi = lane >> 4;

  if (blockIdx.z < 2) {
    unsigned short* C = (blockIdx.z == 0) ? Qp : Kp;
    const float scale = (blockIdx.z == 0) ? 0.18033688011112042f : 1.0f; // 0.125*log2(e)
#pragma unroll
    for (int i = 0; i < 4; i++) {
      int row0 = tm + wm * 64 + i * 16 + hi * 4;
#pragma unroll
      for (int j = 0; j < 4; j++) {
        int col = tn + wn * 64 + j * 16 + l16;
        float bv2 = bias[col];
#pragma unroll
        for (int r = 0; r < 4; r++)
          C[(size_t)(row0 + r) * 1024 + col] = f2bf((acc[i][j][r] + bv2) * scale);
      }
    }
  } else {
    // transposed V write: lane's 4 rows are 4 consecutive s -> one 8B store
#pragma unroll
    for (int i = 0; i < 4; i++) {
      int row0 = tm + wm * 64 + i * 16 + hi * 4;
      int bb = row0 >> 11, s = row0 & 2047;
#pragma unroll
      for (int j = 0; j < 4; j++) {
        int col = tn + wn * 64 + j * 16 + l16;
        int hh = col >> 6, d = col & 63;
        float bv2 = bias[col];
        u32x2 w;
        w[0] = cvtpk(acc[i][j][0] + bv2, acc[i][j][1] + bv2);
        w[1] = cvtpk(acc[i][j][2] + bv2, acc[i][j][3] + bv2);
        *(u32x2*)&Vt[((size_t)(bb * 16 + hh) * 64 + d) * 2048 + s] = w;
      }
    }
  }
}

// Grid (16, 32). XCD = x%8. Pin each Yb A-panel's 16 sharers to one XCD.
__global__ __launch_bounds__(256, 2) void out_gemm(
    const unsigned short* Yb, const unsigned short* wob, const float* bo, float* out)
{
  const int xd = blockIdx.x, yd = blockIdx.y;
  const int mt = (xd & 7) + 8 * (yd & 3);   // 0..31, pinned to XCD xd&7
  const int nt = (xd >> 3) + 2 * (yd >> 2); // 0..15
  const int tm = mt * 128, tn = nt * 64;

  f32x4 acc[2][4] = {};
  gemm_bt_main<128, 64, 4, 1>(Yb, wob, acc, tm, tn);

  const int tid = threadIdx.x, wave = tid >> 6, lane = tid & 63;
  const int l16 = lane & 15, hi = lane >> 4;
#pragma unroll
  for (int i = 0; i < 2; i++) {
    int row0 = tm + wave * 32 + i * 16 + hi * 4;
#pragma unroll
    for (int j = 0; j < 4; j++) {
      int col = tn + j * 16 + l16;
      float bv2 = bo[col];
#pragma unroll
      for (int r = 0; r < 4; r++)
        out[(size_t)(row0 + r) * 1024 + col] = acc[i][j][r] + bv2;
    }
  }
}

// ---------------------------------------------------------------- flash attention
// IN-BLOCK KV-SPLIT: 8 waves x 32 q-rows; waves 0-3 do kv[0,1024), waves 4-7 do
// kv[1024,2048) for the SAME 128 q. KVBLK=64 per half, double-buffered (64KB LDS
// -> 2 blocks/CU -> 16 waves/CU = 4/SIMD). Constant-max softmax (exp2(s-16),
// associative) -> halves combine via LDS O-buffer. RACE FIX vs r14: Q is staged
// into the two K1 buffers (smem+4096, smem+12288) which are provably idle during
// the prologue (first written at t=0, after the frag-read lgkmcnt(0)+barrier);
// previously Q overlapped half-0's K0 destination -> async corruption.
__global__ __launch_bounds__(512, 2) void attn_kernel(
    const unsigned short* __restrict__ Qp, const unsigned short* __restrict__ Kp,
    const unsigned short* __restrict__ Vt, const int* __restrict__ mask,
    unsigned short* __restrict__ Yb)
{
  constexpr int S = 2048, H = 1024;
  __shared__ __align__(16) unsigned short smem[32768];   // 64KB
  // layout (shorts): K half h buf b -> smem + (h*2+b)*4096 ; V -> smem+16384 + (h*2+b)*4096
  // prologue Q staging: rows 0..63 -> smem+4096 (half0 K1), rows 64..127 -> smem+12288 (half1 K1)
  // epilogue: sO f32[128][66] + sL f32[128] over smem (post-barrier reuse)

  const int tid = threadIdx.x, wave = tid >> 6, lane = tid & 63;
  const int l16 = lane & 15, hi = lane >> 4, swz = l16 & 7;
  const int half = wave >> 2, w4 = wave & 3;
  const int kvoff = half * 1024;
  const int xd = blockIdx.x, hd = blockIdx.y;
  const int h  = (xd & 7) + 8 * (hd & 1);            // pinned to XCD xd&7
  const int qt = ((xd >> 3) + 2 * (hd >> 1)) * 128;  // 0..15 q-tile
  const int b = blockIdx.z, bh = b * 16 + h;
  const unsigned short* Qb = Qp + (size_t)b * S * H + (size_t)h * 64;
  const unsigned short* Kb = Kp + (size_t)b * S * H + (size_t)h * 64;
  const unsigned short* Vb = Vt + (size_t)bh * 64 * 2048;

  unsigned short* sK0 = smem + (half * 2) * 4096;        // K buf0
  unsigned short* sK1 = smem + (half * 2 + 1) * 4096;    // K buf1
  unsigned short* sV0 = smem + 16384 + (half * 2) * 4096;
  unsigned short* sV1 = smem + 16384 + (half * 2 + 1) * 4096;

  // loop-invariant LDS read offsets (shorts; row stride 64)
  const int kinv0 = l16 * 64 + ((hi ^ swz) * 8);
  const int kinv1 = l16 * 64 + (((4 + hi) ^ swz) * 8);
  const int vinv0 = kinv0, vinv1 = kinv1;

  // ---- stage Q (128x64 = 16KB) into the two K1 bufs while K0/V0 prefetch
  {
    unsigned short* qdst0 = smem + 4096;    // rows 0..63
    unsigned short* qdst1 = smem + 12288;   // rows 64..127
#pragma unroll
    for (int i = 0; i < 2; i++) {
      int p = i * 512 + tid, row = p >> 3, c = p & 7;
      load_lds16(Qb + (size_t)(qt + row) * H + ((c ^ (row & 7)) * 8),
                 &(i ? qdst1 : qdst0)[(wave * 64) * 8]);
    }
  }
  // per-thread staging source pointers (advance by constants per tile)
  const int htid = tid & 255;
  const unsigned short* pK[2]; const unsigned short* pV[2];
#pragma unroll
  for (int j = 0; j < 2; j++) {
    int g = j * 256 + htid;
    int row = g >> 3, c = g & 7;
    pK[j] = Kb + (size_t)(kvoff + row) * H + ((c ^ (row & 7)) * 8);
    int d = g >> 3, kvc = g & 7;
    int sg = kvc ^ (d & 7);
    pV[j] = Vb + (size_t)d * 2048 + kvoff + sg * 8;
  }
#pragma unroll
  for (int j = 0; j < 2; j++)
    load_lds16(pK[j], &sK0[(j * 256 + w4 * 64) * 8]);
#pragma unroll
  for (int j = 0; j < 2; j++)
    load_lds16(pV[j], &sV0[(j * 256 + w4 * 64) * 8]);
#pragma unroll
  for (int j = 0; j < 2; j++) { pK[j] += 64 * H; pV[j] += 64; }

  asm volatile("s_waitcnt vmcnt(4)" ::: "memory");  // Q landed; K0/V0 still in flight
  __builtin_amdgcn_sched_barrier(0);
  __builtin_amdgcn_s_barrier();

  bf16x8 qf[2][2];
#pragma unroll
  for (int m = 0; m < 2; m++) {
    const int row = w4 * 32 + m * 16 + l16;
    const int qm = mask[(size_t)b * S + qt + row];   // query-axis mask (matches ref)
    const unsigned short* qsrc = (row < 64) ? (smem + 4096 + row * 64)
                                            : (smem + 12288 + (row - 64) * 64);
#pragma unroll
    for (int ks = 0; ks < 2; ks++) {
      bf16x8 v = *(const bf16x8*)&qsrc[((ks * 4 + hi) ^ swz) * 8];
      u32x4 u = __builtin_bit_cast(u32x4, v);
#pragma unroll
      for (int c = 0; c < 4; c++) u[c] = qm ? u[c] : 0u;
      qf[m][ks] = __builtin_bit_cast(bf16x8, u);
    }
  }
  // Q-frag LDS reads must land before t=0 staging overwrites the K1 bufs
  asm volatile("s_waitcnt lgkmcnt(0)" ::: "memory");
  __builtin_amdgcn_sched_barrier(0);
  __builtin_amdgcn_s_barrier();

  float lsum[2] = {0.f, 0.f};
  f32x4 oacc[2][4] = {};

  for (int t = 0; t < 16; t++) {
    const int cur = t & 1;
    // issue next-tile staging, then wait only for the CURRENT tile (counted vmcnt)
    if (t < 15) {
      unsigned short* nK = cur ? sK0 : sK1;
      unsigned short* nV = cur ? sV0 : sV1;
#pragma unroll
      for (int j = 0; j < 2; j++)
        load_lds16(pK[j], &nK[(j * 256 + w4 * 64) * 8]);
#pragma unroll
      for (int j = 0; j < 2; j++)
        load_lds16(pV[j], &nV[(j * 256 + w4 * 64) * 8]);
#pragma unroll
      for (int j = 0; j < 2; j++) { pK[j] += 64 * H; pV[j] += 64; }
      asm volatile("s_waitcnt vmcnt(4)" ::: "memory");
    } else {
      asm volatile("s_waitcnt vmcnt(0)" ::: "memory");
    }
    __builtin_amdgcn_sched_barrier(0);
    __builtin_amdgcn_s_barrier();

    const unsigned short* kb = cur ? sK1 : sK0;
    const unsigned short* vb = cur ? sV1 : sV0;

    // ---- QK^T swapped (64 kv): sf[m][jj] = S - 16 (log2 domain, C-init bake)
    f32x4 sf[2][4];
    __builtin_amdgcn_s_setprio(1);
#pragma unroll
    for (int jj = 0; jj < 4; jj++) {
      const int ro = jj * 1024;
      bf16x8 kf0 = *(const bf16x8*)&kb[ro + kinv0];
      bf16x8 kf1 = *(const bf16x8*)&kb[ro + kinv1];
#pragma unroll
      for (int m = 0; m < 2; m++) {
        f32x4 acc = {-16.0f, -16.0f, -16.0f, -16.0f};
        acc = __builtin_amdgcn_mfma_f32_16x16x32_bf16(kf0, qf[m][0], acc, 0, 0, 0);
        acc = __builtin_amdgcn_mfma_f32_16x16x32_bf16(kf1, qf[m][1], acc, 0, 0, 0);
        sf[m][jj] = acc;
      }
    }
    __builtin_amdgcn_s_setprio(0);

    // ---- constant-max softmax: P = exp2(s')
#pragma unroll
    for (int m = 0; m < 2; m++) {
#pragma unroll
      for (int jj = 0; jj < 4; jj++)
#pragma unroll
        for (int r = 0; r < 4; r++)
          sf[m][jj][r] = fexp2(sf[m][jj][r]);
      f32x4 c4 = (sf[m][0] + sf[m][1]) + (sf[m][2] + sf[m][3]);
      lsum[m] += (c4[0] + c4[1]) + (c4[2] + c4[3]);
    }

    // ---- P repack (permlane) + PV per 32-kv window; V-frag shared across m
#pragma unroll
    for (int w2 = 0; w2 < 2; w2++) {
      bf16x8 af0 = repack_af(sf[0][2 * w2], sf[0][2 * w2 + 1]);
      bf16x8 af1 = repack_af(sf[1][2 * w2], sf[1][2 * w2 + 1]);
      const int vo = w2 ? vinv1 : vinv0;
      __builtin_amdgcn_s_setprio(1);
#pragma unroll
      for (int n = 0; n < 4; n++) {
        bf16x8 vf = *(const bf16x8*)&vb[n * 1024 + vo];
        oacc[0][n] = __builtin_amdgcn_mfma_f32_16x16x32_bf16(af0, vf, oacc[0][n], 0, 0, 0);
        oacc[1][n] = __builtin_amdgcn_mfma_f32_16x16x32_bf16(af1, vf, oacc[1][n], 0, 0, 0);
      }
      __builtin_amdgcn_s_setprio(0);
    }
    __builtin_amdgcn_sched_barrier(0);
    __builtin_amdgcn_s_barrier();
  }

  // ---- epilogue: reduce lsum across hi groups; combine halves via LDS
#pragma unroll
  for (int m = 0; m < 2; m++) {
    lsum[m] += __shfl_xor(lsum[m], 16);
    lsum[m] += __shfl_xor(lsum[m], 32);
  }

  float* sO = (float*)smem;                 // [128][66] f32 = 33792B
  float* sL = (float*)(smem + 16896);       // 128 f32 (byte offset 33792)

  if (half == 1) {
#pragma unroll
    for (int m = 0; m < 2; m++) {
      if (hi == 0) sL[w4 * 32 + m * 16 + l16] = lsum[m];
#pragma unroll
      for (int n = 0; n < 4; n++)
#pragma unroll
        for (int r = 0; r < 4; r++) {
          int qq = w4 * 32 + m * 16 + hi * 4 + r;
          sO[qq * 66 + n * 16 + l16] = oacc[m][n][r];
        }
    }
  }
  __syncthreads();
  if (half == 0) {
#pragma unroll
    for (int m = 0; m < 2; m++) {
      float lt = lsum[m] + sL[w4 * 32 + m * 16 + l16];
      float lr[4];
#pragma unroll
      for (int r = 0; r < 4; r++) lr[r] = 1.0f / __shfl(lt, hi * 4 + r);
#pragma unroll
      for (int n = 0; n < 4; n++)
#pragma unroll
        for (int r = 0; r < 4; r++) {
          int qq = w4 * 32 + m * 16 + hi * 4 + r;
          int col = n * 16 + l16;
          float val = (oacc[m][n][r] + sO[qq * 66 + col]) * lr[r];
          Yb[((size_t)b * S + qt + qq) * H + h * 64 + col] = f2bf(val);
        }
    }
  }
}

// ---------------------------------------------------------------- launch
extern "C" void kernel_launch(void* const* d_in, const int* in_sizes, int n_in,
                              void* d_out, int out_size, void* d_ws, size_t ws_size,
                              hipStream_t stream)
{
  const float* q  = (const float*)d_in[0];
  const float* k  = (const float*)d_in[1];
  const float* v  = (const float*)d_in[2];
  const int*  mask = (const int*)d_in[3];
  const float* Wq = (const float*)d_in[4];
  const float* bq = (const float*)d_in[5];
  const float* Wk = (const float*)d_in[6];
  const float* bk = (const float*)d_in[7];
  const float* Wv = (const float*)d_in[8];
  const float* bv = (const float*)d_in[9];
  const float* Wo = (const float*)d_in[10];
  const float* bo = (const float*)d_in[11];

  unsigned short* ws  = (unsigned short*)d_ws;
  unsigned short* qb  = ws;                 //  0..4  EL
  unsigned short* kb  = ws + 4 * EL;        //  4..8
  unsigned short* vb  = ws + 8 * EL;        //  8..12
  unsigned short* wqb = ws + 12 * EL;       // 12..13
  unsigned short* wkb = ws + 13 * EL;       // 13..14
  unsigned short* wvb = ws + 14 * EL;       // 14..15
  unsigned short* wob = ws + 15 * EL;       // 15..16
  unsigned short* Qp  = ws + 16 * EL;       // 16..20
  unsigned short* Kp  = ws + 20 * EL;       // 20..24
  unsigned short* Vt  = ws + 24 * EL;       // 24..28  [32][64][2048] bf16
  unsigned short* Yb  = ws + 28 * EL;       // 28..32

  convert_all<<<2048, 256, 0, stream>>>(q, k, v, Wq, Wk, Wv, Wo, ws);
  qkv_gemm<<<dim3(8, 32, 3), 256, 0, stream>>>(qb, kb, vb, wqb, wkb, wvb,
                                               bq, bk, bv, Qp, Kp, Vt);
  attn_kernel<<<dim3(16, 16, 2), 512, 0, stream>>>(Qp, Kp, Vt, mask, Yb);
  out_gemm<<<dim3(16, 32), 256, 0, stream>>>(Yb, wob, bo, (float*)d_out);
}

// Round 16
// 104.068 us; speedup vs baseline: 1.3652x; 1.0069x over previous
//
#include <hip/hip_runtime.h>
#include <hip/hip_bf16.h>
#include <cstdint>

#define EL 1048576ull   // 1Mi elements

typedef __bf16 bf16_t;
typedef bf16_t bf16x8 __attribute__((ext_vector_type(8)));
typedef float  f32x4  __attribute__((ext_vector_type(4)));
typedef unsigned int u32x2 __attribute__((ext_vector_type(2)));
typedef unsigned int u32x4 __attribute__((ext_vector_type(4)));

__device__ __forceinline__ unsigned short f2bf(float f) {
  unsigned int u = __builtin_bit_cast(unsigned int, f);
  u += 0x7FFFu + ((u >> 16) & 1u);   // RNE
  return (unsigned short)(u >> 16);
}

// pack 2 f32 -> 2 bf16 in one u32 (lo -> low half), RNE; proven round 5
__device__ __forceinline__ unsigned int cvtpk(float lo, float hi2) {
  unsigned int r;
  asm("v_cvt_pk_bf16_f32 %0, %1, %2" : "=v"(r) : "v"(lo), "v"(hi2));
  return r;
}

__device__ __forceinline__ float fexp2(float x) {
#if __has_builtin(__builtin_amdgcn_exp2f)
  return __builtin_amdgcn_exp2f(x);
#else
  return exp2f(x);
#endif
}

typedef __attribute__((address_space(1))) void as1_void;
typedef __attribute__((address_space(3))) void as3_void;
__device__ __forceinline__ void load_lds16(const void* g, void* l) {
  __builtin_amdgcn_global_load_lds((as1_void*)g, (as3_void*)l, 16, 0, 0);
}

// P repack via permlane swaps (VALU, no LDS pipe); proven round 6
__device__ __forceinline__ bf16x8 repack_af(const f32x4 s0v, const f32x4 s1v) {
  unsigned int c00 = cvtpk(s0v[0], s0v[1]);
  unsigned int c01 = cvtpk(s0v[2], s0v[3]);
  unsigned int c10 = cvtpk(s1v[0], s1v[1]);
  unsigned int c11 = cvtpk(s1v[2], s1v[3]);
  asm("v_permlane32_swap_b32 %0, %1" : "+v"(c00), "+v"(c10));
  asm("v_permlane16_swap_b32 %0, %1" : "+v"(c00), "+v"(c10));
  asm("v_permlane32_swap_b32 %0, %1" : "+v"(c01), "+v"(c11));
  asm("v_permlane16_swap_b32 %0, %1" : "+v"(c01), "+v"(c11));
  u32x4 wd; wd[0] = c00; wd[1] = c01; wd[2] = c10; wd[3] = c11;
  return __builtin_bit_cast(bf16x8, wd);
}

// ---------------------------------------------------------------- convert
__global__ __launch_bounds__(256) void convert_all(
    const float* __restrict__ q, const float* __restrict__ k, const float* __restrict__ v,
    const float* __restrict__ wq, const float* __restrict__ wk,
    const float* __restrict__ wv, const float* __restrict__ wo,
    unsigned short* __restrict__ ws)
{
  const size_t total_v4 = 4 * EL; // 16M elems / 4
  for (size_t v4 = (size_t)blockIdx.x * blockDim.x + threadIdx.x; v4 < total_v4;
       v4 += (size_t)gridDim.x * blockDim.x) {
    size_t e = v4 * 4;
    unsigned seg = (unsigned)(e >> 20);
    const float* s; size_t base;
    if      (seg < 4)   { s = q;  base = 0; }
    else if (seg < 8)   { s = k;  base = 4*EL; }
    else if (seg < 12)  { s = v;  base = 8*EL; }
    else if (seg == 12) { s = wq; base = 12*EL; }
    else if (seg == 13) { s = wk; base = 13*EL; }
    else if (seg == 14) { s = wv; base = 14*EL; }
    else                { s = wo; base = 15*EL; }
    const float4 f = *(const float4*)(s + (e - base));
    ushort4 o;
    o.x = f2bf(f.x); o.y = f2bf(f.y); o.z = f2bf(f.z); o.w = f2bf(f.w);
    *(ushort4*)(ws + e) = o;
  }
}

// ---------------------------------------------------------------- GEMM main loop (acc += A * B^T)
template <int BM, int BN, int WM, int WN>
__device__ __forceinline__ void gemm_bt_main(
    const unsigned short* __restrict__ A,
    const unsigned short* __restrict__ B,
    f32x4 (&acc)[BM / WM / 16][BN / WN / 16],
    const int tm, const int tn)
{
  constexpr int K = 1024, BK = 64;
  constexpr int AM = BM / WM / 16, AN = BN / WN / 16;
  __shared__ __align__(16) unsigned short sA[BM * BK];
  __shared__ __align__(16) unsigned short sB[BN * BK];
  const int tid  = threadIdx.x;
  const int wave = tid >> 6, lane = tid & 63;
  const int wm = wave / WN, wn = wave % WN;
  const int l16 = lane & 15, hi = lane >> 4, swz = l16 & 7;

  for (int k0 = 0; k0 < K; k0 += BK) {
    __syncthreads();
#pragma unroll
    for (int i = 0; i < BM * 8 / 256; i++) {
      int p = i * 256 + tid;
      int row = p >> 3, c = p & 7;
      load_lds16(A + (size_t)(tm + row) * K + k0 + ((c ^ (row & 7)) * 8),
                 &sA[(i * 256 + wave * 64) * 8]);
    }
#pragma unroll
    for (int i = 0; i < BN * 8 / 256; i++) {
      int p = i * 256 + tid;
      int row = p >> 3, c = p & 7;
      load_lds16(B + (size_t)(tn + row) * K + k0 + ((c ^ (row & 7)) * 8),
                 &sB[(i * 256 + wave * 64) * 8]);
    }
    __syncthreads();

#pragma unroll
    for (int kk = 0; kk < 2; kk++) {
      bf16x8 af[AM], bfr[AN];
#pragma unroll
      for (int i = 0; i < AM; i++) {
        int row = wm * (BM / WM) + i * 16 + l16;
        af[i] = *(const bf16x8*)&sA[row * BK + (((kk * 4 + hi) ^ swz) * 8)];
      }
#pragma unroll
      for (int j = 0; j < AN; j++) {
        int row = wn * (BN / WN) + j * 16 + l16;
        bfr[j] = *(const bf16x8*)&sB[row * BK + (((kk * 4 + hi) ^ swz) * 8)];
      }
#pragma unroll
      for (int i = 0; i < AM; i++)
#pragma unroll
        for (int j = 0; j < AN; j++)
          acc[i][j] = __builtin_amdgcn_mfma_f32_16x16x32_bf16(af[i], bfr[j], acc[i][j], 0, 0, 0);
    }
  }
}

// ---------------------------------------------------------------- QKV projections
// Grid (8, 32, 3). XCD = blockIdx.x. A-panel's 8 sharers pinned to one XCD.
__global__ __launch_bounds__(256, 3) void qkv_gemm(
    const unsigned short* qb, const unsigned short* kb, const unsigned short* vb,
    const unsigned short* wqb, const unsigned short* wkb, const unsigned short* wvb,
    const float* bq, const float* bk, const float* bv,
    unsigned short* Qp, unsigned short* Kp, unsigned short* Vt)
{
  const unsigned short* A; const unsigned short* B; const float* bias;
  if (blockIdx.z == 0)      { A = qb; B = wqb; bias = bq; }
  else if (blockIdx.z == 1) { A = kb; B = wkb; bias = bk; }
  else                      { A = vb; B = wvb; bias = bv; }

  const int xd = blockIdx.x, yd = blockIdx.y;
  const int mt = xd + 8 * (yd & 3);    // A-panel id 0..31, pinned to XCD xd
  const int nt = yd >> 2;              // 0..7
  const int tm = mt * 128, tn = nt * 128;

  f32x4 acc[4][4] = {};
  gemm_bt_main<128, 128, 2, 2>(A, B, acc, tm, tn);

  const int tid = threadIdx.x, wave = tid >> 6, lane = tid & 63;
  const int wm = wave >> 1, wn = wave & 1;
  const int l16 = lane & 15, hi = lane >> 4;

  if (blockIdx.z < 2) {
    unsigned short* C = (blockIdx.z == 0) ? Qp : Kp;
    const float scale = (blockIdx.z == 0) ? 0.18033688011112042f : 1.0f; // 0.125*log2(e)
#pragma unroll
    for (int i = 0; i < 4; i++) {
      int row0 = tm + wm * 64 + i * 16 + hi * 4;
#pragma unroll
      for (int j = 0; j < 4; j++) {
        int col = tn + wn * 64 + j * 16 + l16;
        float bv2 = bias[col];
#pragma unroll
        for (int r = 0; r < 4; r++)
          C[(size_t)(row0 + r) * 1024 + col] = f2bf((acc[i][j][r] + bv2) * scale);
      }
    }
  } else {
    // transposed V write: lane's 4 rows are 4 consecutive s -> one 8B store
#pragma unroll
    for (int i = 0; i < 4; i++) {
      int row0 = tm + wm * 64 + i * 16 + hi * 4;
      int bb = row0 >> 11, s = row0 & 2047;
#pragma unroll
      for (int j = 0; j < 4; j++) {
        int col = tn + wn * 64 + j * 16 + l16;
        int hh = col >> 6, d = col & 63;
        float bv2 = bias[col];
        u32x2 w;
        w[0] = cvtpk(acc[i][j][0] + bv2, acc[i][j][1] + bv2);
        w[1] = cvtpk(acc[i][j][2] + bv2, acc[i][j][3] + bv2);
        *(u32x2*)&Vt[((size_t)(bb * 16 + hh) * 64 + d) * 2048 + s] = w;
      }
    }
  }
}

// Grid (16, 32). XCD = x%8. Pin each Yb A-panel's 16 sharers to one XCD.
__global__ __launch_bounds__(256, 2) void out_gemm(
    const unsigned short* Yb, const unsigned short* wob, const float* bo, float* out)
{
  const int xd = blockIdx.x, yd = blockIdx.y;
  const int mt = (xd & 7) + 8 * (yd & 3);   // 0..31, pinned to XCD xd&7
  const int nt = (xd >> 3) + 2 * (yd >> 2); // 0..15
  const int tm = mt * 128, tn = nt * 64;

  f32x4 acc[2][4] = {};
  gemm_bt_main<128, 64, 4, 1>(Yb, wob, acc, tm, tn);

  const int tid = threadIdx.x, wave = tid >> 6, lane = tid & 63;
  const int l16 = lane & 15, hi = lane >> 4;
#pragma unroll
  for (int i = 0; i < 2; i++) {
    int row0 = tm + wave * 32 + i * 16 + hi * 4;
#pragma unroll
    for (int j = 0; j < 4; j++) {
      int col = tn + j * 16 + l16;
      float bv2 = bo[col];
#pragma unroll
      for (int r = 0; r < 4; r++)
        out[(size_t)(row0 + r) * 1024 + col] = acc[i][j][r] + bv2;
    }
  }
}

// ---------------------------------------------------------------- flash attention
// IN-BLOCK KV-SPLIT + SINGLE-BARRIER PIPELINE. 8 waves x 32 q-rows; waves 0-3 do
// kv[0,1024), waves 4-7 kv[1024,2048) for the SAME 128 q. KVBLK=64 per half,
// double-buffered. Loop structure (T3 minimum-2-phase): per tile ONE barrier:
//   vmcnt(0) [stage(t) landed, covered by compute(t-1)] -> s_barrier [RAW+WAR]
//   -> issue stage(t+1) -> compute(t).
// Constant-max softmax (exp2(s-16), associative) -> halves combine via LDS.
__global__ __launch_bounds__(512, 2) void attn_kernel(
    const unsigned short* __restrict__ Qp, const unsigned short* __restrict__ Kp,
    const unsigned short* __restrict__ Vt, const int* __restrict__ mask,
    unsigned short* __restrict__ Yb)
{
  constexpr int S = 2048, H = 1024;
  __shared__ __align__(16) unsigned short smem[32768];   // 64KB
  // layout (shorts): K half h buf b -> smem + (h*2+b)*4096 ; V -> smem+16384 + (h*2+b)*4096
  // prologue Q staging: rows 0..63 -> smem+4096 (half0 K1), rows 64..127 -> smem+12288 (half1 K1)
  // epilogue: sO f32[128][66] + sL f32[128] over smem (post-barrier reuse)

  const int tid = threadIdx.x, wave = tid >> 6, lane = tid & 63;
  const int l16 = lane & 15, hi = lane >> 4, swz = l16 & 7;
  const int half = wave >> 2, w4 = wave & 3;
  const int kvoff = half * 1024;
  const int xd = blockIdx.x, hd = blockIdx.y;
  const int h  = (xd & 7) + 8 * (hd & 1);            // pinned to XCD xd&7
  const int qt = ((xd >> 3) + 2 * (hd >> 1)) * 128;  // 0..15 q-tile
  const int b = blockIdx.z, bh = b * 16 + h;
  const unsigned short* Qb = Qp + (size_t)b * S * H + (size_t)h * 64;
  const unsigned short* Kb = Kp + (size_t)b * S * H + (size_t)h * 64;
  const unsigned short* Vb = Vt + (size_t)bh * 64 * 2048;

  unsigned short* sK0 = smem + (half * 2) * 4096;        // K buf0
  unsigned short* sK1 = smem + (half * 2 + 1) * 4096;    // K buf1
  unsigned short* sV0 = smem + 16384 + (half * 2) * 4096;
  unsigned short* sV1 = smem + 16384 + (half * 2 + 1) * 4096;

  // loop-invariant LDS read offsets (shorts; row stride 64)
  const int kinv0 = l16 * 64 + ((hi ^ swz) * 8);
  const int kinv1 = l16 * 64 + (((4 + hi) ^ swz) * 8);
  const int vinv0 = kinv0, vinv1 = kinv1;

  // ---- stage Q (128x64 = 16KB) into the two K1 bufs while K0/V0 prefetch
  {
    unsigned short* qdst0 = smem + 4096;    // rows 0..63
    unsigned short* qdst1 = smem + 12288;   // rows 64..127
#pragma unroll
    for (int i = 0; i < 2; i++) {
      int p = i * 512 + tid, row = p >> 3, c = p & 7;
      load_lds16(Qb + (size_t)(qt + row) * H + ((c ^ (row & 7)) * 8),
                 &(i ? qdst1 : qdst0)[(wave * 64) * 8]);
    }
  }
  // per-thread staging source pointers (advance by constants per tile)
  const int htid = tid & 255;
  const unsigned short* pK[2]; const unsigned short* pV[2];
#pragma unroll
  for (int j = 0; j < 2; j++) {
    int g = j * 256 + htid;
    int row = g >> 3, c = g & 7;
    pK[j] = Kb + (size_t)(kvoff + row) * H + ((c ^ (row & 7)) * 8);
    int d = g >> 3, kvc = g & 7;
    int sg = kvc ^ (d & 7);
    pV[j] = Vb + (size_t)d * 2048 + kvoff + sg * 8;
  }
#pragma unroll
  for (int j = 0; j < 2; j++)
    load_lds16(pK[j], &sK0[(j * 256 + w4 * 64) * 8]);
#pragma unroll
  for (int j = 0; j < 2; j++)
    load_lds16(pV[j], &sV0[(j * 256 + w4 * 64) * 8]);
#pragma unroll
  for (int j = 0; j < 2; j++) { pK[j] += 64 * H; pV[j] += 64; }

  asm volatile("s_waitcnt vmcnt(4)" ::: "memory");  // Q landed; K0/V0 still in flight
  __builtin_amdgcn_sched_barrier(0);
  __builtin_amdgcn_s_barrier();                     // all waves' Q visible

  bf16x8 qf[2][2];
#pragma unroll
  for (int m = 0; m < 2; m++) {
    const int row = w4 * 32 + m * 16 + l16;
    const int qm = mask[(size_t)b * S + qt + row];   // query-axis mask (matches ref)
    const unsigned short* qsrc = (row < 64) ? (smem + 4096 + row * 64)
                                            : (smem + 12288 + (row - 64) * 64);
#pragma unroll
    for (int ks = 0; ks < 2; ks++) {
      bf16x8 v = *(const bf16x8*)&qsrc[((ks * 4 + hi) ^ swz) * 8];
      u32x4 u = __builtin_bit_cast(u32x4, v);
#pragma unroll
      for (int c = 0; c < 4; c++) u[c] = qm ? u[c] : 0u;
      qf[m][ks] = __builtin_bit_cast(bf16x8, u);
    }
  }
  // Q-frag LDS reads must complete before any wave stages t=1 into the K1 bufs;
  // each wave drains its own reads here, the t=0 loop barrier globalizes it.
  asm volatile("s_waitcnt lgkmcnt(0)" ::: "memory");
  __builtin_amdgcn_sched_barrier(0);

  float lsum[2] = {0.f, 0.f};
  f32x4 oacc[2][4] = {};

  for (int t = 0; t < 16; t++) {
    const int cur = t & 1;
    // single-barrier pipeline point: stage(t) landed everywhere + compute(t-1)
    // finished everywhere (and at t=0: Q-frag reads done everywhere).
    asm volatile("s_waitcnt vmcnt(0)" ::: "memory");
    __builtin_amdgcn_sched_barrier(0);
    __builtin_amdgcn_s_barrier();

    // issue next-tile staging immediately; it lands during compute(t)
    if (t < 15) {
      unsigned short* nK = cur ? sK0 : sK1;
      unsigned short* nV = cur ? sV0 : sV1;
#pragma unroll
      for (int j = 0; j < 2; j++)
        load_lds16(pK[j], &nK[(j * 256 + w4 * 64) * 8]);
#pragma unroll
      for (int j = 0; j < 2; j++)
        load_lds16(pV[j], &nV[(j * 256 + w4 * 64) * 8]);
#pragma unroll
      for (int j = 0; j < 2; j++) { pK[j] += 64 * H; pV[j] += 64; }
    }

    const unsigned short* kb = cur ? sK1 : sK0;
    const unsigned short* vb = cur ? sV1 : sV0;

    // ---- QK^T swapped (64 kv): sf[m][jj] = S - 16 (log2 domain, C-init bake)
    f32x4 sf[2][4];
    __builtin_amdgcn_s_setprio(1);
#pragma unroll
    for (int jj = 0; jj < 4; jj++) {
      const int ro = jj * 1024;
      bf16x8 kf0 = *(const bf16x8*)&kb[ro + kinv0];
      bf16x8 kf1 = *(const bf16x8*)&kb[ro + kinv1];
#pragma unroll
      for (int m = 0; m < 2; m++) {
        f32x4 acc = {-16.0f, -16.0f, -16.0f, -16.0f};
        acc = __builtin_amdgcn_mfma_f32_16x16x32_bf16(kf0, qf[m][0], acc, 0, 0, 0);
        acc = __builtin_amdgcn_mfma_f32_16x16x32_bf16(kf1, qf[m][1], acc, 0, 0, 0);
        sf[m][jj] = acc;
      }
    }
    __builtin_amdgcn_s_setprio(0);

    // ---- constant-max softmax: P = exp2(s')
#pragma unroll
    for (int m = 0; m < 2; m++) {
#pragma unroll
      for (int jj = 0; jj < 4; jj++)
#pragma unroll
        for (int r = 0; r < 4; r++)
          sf[m][jj][r] = fexp2(sf[m][jj][r]);
      f32x4 c4 = (sf[m][0] + sf[m][1]) + (sf[m][2] + sf[m][3]);
      lsum[m] += (c4[0] + c4[1]) + (c4[2] + c4[3]);
    }

    // ---- P repack (permlane) + PV per 32-kv window; V-frag shared across m
#pragma unroll
    for (int w2 = 0; w2 < 2; w2++) {
      bf16x8 af0 = repack_af(sf[0][2 * w2], sf[0][2 * w2 + 1]);
      bf16x8 af1 = repack_af(sf[1][2 * w2], sf[1][2 * w2 + 1]);
      const int vo = w2 ? vinv1 : vinv0;
      __builtin_amdgcn_s_setprio(1);
#pragma unroll
      for (int n = 0; n < 4; n++) {
        bf16x8 vf = *(const bf16x8*)&vb[n * 1024 + vo];
        oacc[0][n] = __builtin_amdgcn_mfma_f32_16x16x32_bf16(af0, vf, oacc[0][n], 0, 0, 0);
        oacc[1][n] = __builtin_amdgcn_mfma_f32_16x16x32_bf16(af1, vf, oacc[1][n], 0, 0, 0);
      }
      __builtin_amdgcn_s_setprio(0);
    }
  }

  // ---- epilogue: reduce lsum across hi groups; combine halves via LDS
#pragma unroll
  for (int m = 0; m < 2; m++) {
    lsum[m] += __shfl_xor(lsum[m], 16);
    lsum[m] += __shfl_xor(lsum[m], 32);
  }

  __syncthreads();   // all waves done reading sK1/sV1 (t=15) before sO overwrite

  float* sO = (float*)smem;                 // [128][66] f32 = 33792B
  float* sL = (float*)(smem + 16896);       // 128 f32 (byte offset 33792)

  if (half == 1) {
#pragma unroll
    for (int m = 0; m < 2; m++) {
      if (hi == 0) sL[w4 * 32 + m * 16 + l16] = lsum[m];
#pragma unroll
      for (int n = 0; n < 4; n++)
#pragma unroll
        for (int r = 0; r < 4; r++) {
          int qq = w4 * 32 + m * 16 + hi * 4 + r;
          sO[qq * 66 + n * 16 + l16] = oacc[m][n][r];
        }
    }
  }
  __syncthreads();
  if (half == 0) {
#pragma unroll
    for (int m = 0; m < 2; m++) {
      float lt = lsum[m] + sL[w4 * 32 + m * 16 + l16];
      float lr[4];
#pragma unroll
      for (int r = 0; r < 4; r++) lr[r] = 1.0f / __shfl(lt, hi * 4 + r);
#pragma unroll
      for (int n = 0; n < 4; n++)
#pragma unroll
        for (int r = 0; r < 4; r++) {
          int qq = w4 * 32 + m * 16 + hi * 4 + r;
          int col = n * 16 + l16;
          float val = (oacc[m][n][r] + sO[qq * 66 + col]) * lr[r];
          Yb[((size_t)b * S + qt + qq) * H + h * 64 + col] = f2bf(val);
        }
    }
  }
}

// ---------------------------------------------------------------- launch
extern "C" void kernel_launch(void* const* d_in, const int* in_sizes, int n_in,
                              void* d_out, int out_size, void* d_ws, size_t ws_size,
                              hipStream_t stream)
{
  const float* q  = (const float*)d_in[0];
  const float* k  = (const float*)d_in[1];
  const float* v  = (const float*)d_in[2];
  const int*  mask = (const int*)d_in[3];
  const float* Wq = (const float*)d_in[4];
  const float* bq = (const float*)d_in[5];
  const float* Wk = (const float*)d_in[6];
  const float* bk = (const float*)d_in[7];
  const float* Wv = (const float*)d_in[8];
  const float* bv = (const float*)d_in[9];
  const float* Wo = (const float*)d_in[10];
  const float* bo = (const float*)d_in[11];

  unsigned short* ws  = (unsigned short*)d_ws;
  unsigned short* qb  = ws;                 //  0..4  EL
  unsigned short* kb  = ws + 4 * EL;        //  4..8
  unsigned short* vb  = ws + 8 * EL;        //  8..12
  unsigned short* wqb = ws + 12 * EL;       // 12..13
  unsigned short* wkb = ws + 13 * EL;       // 13..14
  unsigned short* wvb = ws + 14 * EL;       // 14..15
  unsigned short* wob = ws + 15 * EL;       // 15..16
  unsigned short* Qp  = ws + 16 * EL;       // 16..20
  unsigned short* Kp  = ws + 20 * EL;       // 20..24
  unsigned short* Vt  = ws + 24 * EL;       // 24..28  [32][64][2048] bf16
  unsigned short* Yb  = ws + 28 * EL;       // 28..32

  convert_all<<<2048, 256, 0, stream>>>(q, k, v, Wq, Wk, Wv, Wo, ws);
  qkv_gemm<<<dim3(8, 32, 3), 256, 0, stream>>>(qb, kb, vb, wqb, wkb, wvb,
                                               bq, bk, bv, Qp, Kp, Vt);
  attn_kernel<<<dim3(16, 16, 2), 512, 0, stream>>>(Qp, Kp, Vt, mask, Yb);
  out_gemm<<<dim3(16, 32), 256, 0, stream>>>(Yb, wob, bo, (float*)d_out);
}